// Round 11
// baseline (182.504 us; speedup 1.0000x reference)
//
#include <hip/hip_runtime.h>

#define NN 100000
#define NE 1600000
#define EPSV 1e-5f

#define NBUK 391       // buckets of 256 nodes: bucket = dst >> 8
#define TILE 2048      // edges per k_bin workgroup
#define NTIL 782       // ceil(NE / TILE)
#define CAP  4608      // per-bucket capacity (mean 4092, sigma ~64 -> +8 sigma)

typedef __attribute__((ext_vector_type(8))) short bf16x8;
typedef __attribute__((ext_vector_type(4))) float f32x4;

__device__ inline unsigned short f2bf(float f) {
  unsigned u = __builtin_bit_cast(unsigned, f);
  unsigned r = u + 0x7FFFu + ((u >> 16) & 1u);
  return (unsigned short)(r >> 16);
}
__device__ inline float bf2f(unsigned short s) {
  unsigned u = ((unsigned)s) << 16;
  return __builtin_bit_cast(float, u);
}

// ---------------- phase 1: LDS-binned edge partition ----------------
__global__ __launch_bounds__(256) void k_bin(const int* __restrict__ src,
                                             const int* __restrict__ dst,
                                             int* __restrict__ gcur,
                                             unsigned* __restrict__ pairs) {
  __shared__ int cnt[NBUK];
  __shared__ int lo[NBUK];
  __shared__ int gbase[NBUK];
  __shared__ int ts[256];
  __shared__ unsigned stage[TILE];
  const int tid = threadIdx.x;
  const int e0 = blockIdx.x * TILE;
  const int m = min(TILE, NE - e0);

  for (int i = tid; i < NBUK; i += 256) cnt[i] = 0;
  __syncthreads();
  for (int i = tid; i < m; i += 256) {
    int d = dst[e0 + i];
    atomicAdd(&cnt[d >> 8], 1);
  }
  __syncthreads();
  // 2-elem-per-thread scan of NBUK counts
  const int i0 = 2 * tid, i1 = 2 * tid + 1;
  int c0 = (i0 < NBUK) ? cnt[i0] : 0;
  int c1 = (i1 < NBUK) ? cnt[i1] : 0;
  int s2 = c0 + c1;
  ts[tid] = s2;
  __syncthreads();
  for (int d = 1; d < 256; d <<= 1) {
    int v = (tid >= d) ? ts[tid - d] : 0;
    __syncthreads();
    ts[tid] += v;
    __syncthreads();
  }
  int ex = ts[tid] - s2;
  if (i0 < NBUK) { lo[i0] = ex;      gbase[i0] = atomicAdd(&gcur[i0], c0); }
  if (i1 < NBUK) { lo[i1] = ex + c0; gbase[i1] = atomicAdd(&gcur[i1], c1); }
  __syncthreads();
  if (i0 < NBUK) cnt[i0] = lo[i0];
  if (i1 < NBUK) cnt[i1] = lo[i1];
  __syncthreads();
  for (int i = tid; i < m; i += 256) {
    int d = dst[e0 + i];
    int s = src[e0 + i];
    int b = d >> 8;
    int pos = atomicAdd(&cnt[b], 1);
    stage[pos] = ((unsigned)(d & 255) << 17) | (unsigned)s;
  }
  __syncthreads();
  for (int i = tid; i < m; i += 256) {
    int a = 0, z = NBUK - 1;
    while (a < z) {
      int mid = (a + z + 1) >> 1;
      if (lo[mid] <= i) a = mid; else z = mid - 1;
    }
    int rel = gbase[a] + (i - lo[a]);
    if (rel < CAP) pairs[(size_t)a * CAP + rel] = stage[i];
  }
}

// ---------------- phase 1.5: scan bucket counts ----------------
__global__ __launch_bounds__(256) void k_bscan(const int* __restrict__ gcur,
                                               int* __restrict__ bucketBase) {
  __shared__ int ts[256];
  const int tid = threadIdx.x;
  const int i0 = 2 * tid, i1 = 2 * tid + 1;
  int c0 = (i0 < NBUK) ? min(gcur[i0], CAP) : 0;
  int c1 = (i1 < NBUK) ? min(gcur[i1], CAP) : 0;
  int s2 = c0 + c1;
  ts[tid] = s2;
  __syncthreads();
  for (int d = 1; d < 256; d <<= 1) {
    int v = (tid >= d) ? ts[tid - d] : 0;
    __syncthreads();
    ts[tid] += v;
    __syncthreads();
  }
  int ex = ts[tid] - s2;
  if (i0 < NBUK) bucketBase[i0] = ex;
  if (i1 < NBUK) bucketBase[i1] = ex + c0;
}

// ---------------- phase 2: per-bucket CSR build (512 threads, 391 blocks) ----------------
__global__ __launch_bounds__(512) void k_build(const unsigned* __restrict__ pairs,
                                               const int* __restrict__ gcur,
                                               const int* __restrict__ bucketBase,
                                               int* __restrict__ deg,
                                               int* __restrict__ offset,
                                               int* __restrict__ csr) {
  __shared__ int hist[256];
  __shared__ int ts[256];
  __shared__ unsigned stage[CAP];
  const int tid = threadIdx.x;
  const int b = blockIdx.x;
  const int count = min(gcur[b], CAP);
  const int nbase = b * 256;
  const int nloc = min(256, NN - nbase);
  const unsigned* pb = pairs + (size_t)b * CAP;
  const int obase = bucketBase[b];

  if (tid < 256) hist[tid] = 0;
  __syncthreads();
  for (int i = tid; i < count; i += 512) {
    atomicAdd(&hist[pb[i] >> 17], 1);
  }
  __syncthreads();
  int s = 0;
  if (tid < 256) { s = hist[tid]; ts[tid] = s; }
  __syncthreads();
  for (int d = 1; d < 256; d <<= 1) {
    int v = 0;
    if (tid < 256 && tid >= d) v = ts[tid - d];
    __syncthreads();
    if (tid < 256) ts[tid] += v;
    __syncthreads();
  }
  if (tid < 256) {
    int ex = ts[tid] - s;
    if (tid < nloc) {
      deg[nbase + tid] = s;
      offset[nbase + tid] = obase + ex;
    }
    hist[tid] = ex;  // cursor
  }
  __syncthreads();
  for (int i = tid; i < count; i += 512) {
    unsigned e = pb[i];
    int pos = atomicAdd(&hist[e >> 17], 1);
    stage[pos] = e & 0x1FFFFu;
  }
  __syncthreads();
  for (int i = tid; i < count; i += 512) csr[obase + i] = (int)stage[i];
}

// ---------------- weight + BN-param prep ----------------
// w1c[o][k]: k<64 w1l, k>=64 w1r. w2c[o][k]: o<64 w2l -> t, o>=64 w2r -> r2.
// bn[0..127]=SC1, [128..255]=SH1 (b1l folded), [256..319]=SC2, [320..383]=SH2 (b2l folded).
__global__ __launch_bounds__(256) void k_wprep(const float* __restrict__ w1l,
                                               const float* __restrict__ w1r,
                                               const float* __restrict__ w2l,
                                               const float* __restrict__ w2r,
                                               const float* __restrict__ b1l,
                                               const float* __restrict__ g1,
                                               const float* __restrict__ be1,
                                               const float* __restrict__ m1,
                                               const float* __restrict__ v1,
                                               const float* __restrict__ b2l,
                                               const float* __restrict__ g2,
                                               const float* __restrict__ be2,
                                               const float* __restrict__ m2,
                                               const float* __restrict__ v2,
                                               unsigned short* __restrict__ w1c,
                                               unsigned short* __restrict__ w2c,
                                               float* __restrict__ bn) {
  int i = blockIdx.x * 256 + threadIdx.x;  // 0..16383
  int o = i >> 7, k = i & 127;
  float vv1 = (k < 64) ? w1l[o * 64 + k] : w1r[o * 64 + (k - 64)];
  w1c[i] = f2bf(vv1);
  float vv2 = (o < 64) ? w2l[o * 128 + k] : w2r[(o - 64) * 128 + k];
  w2c[i] = f2bf(vv2);
  if (i < 128) {
    float sc = g1[i] * rsqrtf(v1[i] + EPSV);
    bn[i] = sc;
    bn[128 + i] = (b1l[i] - m1[i]) * sc + be1[i];
  }
  if (i < 64) {
    float sc = g2[i] * rsqrtf(v2[i] + EPSV);
    bn[256 + i] = sc;
    bn[320 + i] = (b2l[i] - m2[i]) * sc + be2[i];
  }
}

// ---------------- convert x -> bf16 ----------------
__global__ __launch_bounds__(256) void k_cvtx(const float* __restrict__ x,
                                              unsigned short* __restrict__ xb) {
  int i = blockIdx.x * 256 + threadIdx.x;
  float4 v = *(const float4*)(x + (size_t)i * 4);
  ushort4 o;
  o.x = f2bf(v.x); o.y = f2bf(v.y); o.z = f2bf(v.z); o.w = f2bf(v.w);
  *(ushort4*)(xb + (size_t)i * 4) = o;
}

// ---------------- fused: aggregate (gather) + layer1 + layer2 MFMA ----------------
// 4 waves/block, 32 nodes/wave, 128 nodes/block.
// LDS: 32KB weights (time-muxed w1->w2) + 32KB h (first 4KB/wave doubles as agg stage)
// + 1.5KB bn = 65.5KB -> 2 blocks/CU. Gather phase of one block overlaps MFMA of the other.
__global__ __launch_bounds__(256) void k_aggemm(const unsigned short* __restrict__ xb,
                                                const int* __restrict__ deg,
                                                const int* __restrict__ offset,
                                                const int* __restrict__ csr,
                                                const unsigned short* __restrict__ w1c,
                                                const unsigned short* __restrict__ w2c,
                                                const float* __restrict__ bn,
                                                unsigned short* __restrict__ t,
                                                unsigned short* __restrict__ r2) {
  __shared__ unsigned short wlds[32 * 512];       // 32KB: frag f at f*512, lane*8
  __shared__ unsigned short hlds[4][2][16 * 128]; // 32KB; first 4KB per wave = agg stage
  __shared__ float bnlds[384];
  const int tid = threadIdx.x;
  const int w = tid >> 6;
  const int lane = tid & 63;
  const int lr = lane & 15;
  const int q = lane >> 4;
  const int base = blockIdx.x * 128 + w * 32;
  const int nA = base + lr, nB = base + 16 + lr;
  const int cA = min(nA, NN - 1), cB = min(nB, NN - 1);
  const int swz = (lr & 7) << 4;

  // stage bn + w1 (fragment-major)
  for (int i = tid; i < 384; i += 256) bnlds[i] = bn[i];
  for (int idx = tid; idx < 2048; idx += 256) {
    int f = idx >> 6, l = idx & 63;
    int gofs = ((f >> 2) * 16 + (l & 15)) * 128 + (f & 3) * 32 + (l >> 4) * 8;
    *(uint4*)&wlds[idx * 8] = *(const uint4*)&w1c[gofs];
  }

  // per-node x fragments (linear reads; in flight during gather)
  bf16x8 fA2, fA3, fB2, fB3;
  fA2 = *(const bf16x8*)(xb + (size_t)cA * 64 + q * 8);
  fA3 = *(const bf16x8*)(xb + (size_t)cA * 64 + q * 8 + 32);
  fB2 = *(const bf16x8*)(xb + (size_t)cB * 64 + q * 8);
  fB3 = *(const bf16x8*)(xb + (size_t)cB * 64 + q * 8 + 32);

  // ---- gather-aggregate this wave's 32 nodes into swizzled agg stage ----
  char* astage = (char*)&hlds[w][0][0];  // 32 nodes x 128B = 4KB (dead before h writes)
  const int jj = lane & 7;   // dim slot: dims jj*8..jj*8+7
  const int sub = lane >> 3; // node sub-index
  for (int pass = 0; pass < 4; ++pass) {
    const int nl = pass * 8 + sub;
    const int cn = min(base + nl, NN - 1);
    const int cnt = deg[cn];
    const int* arow = csr + offset[cn];
    float a0=0.f,a1=0.f,a2=0.f,a3=0.f,a4=0.f,a5=0.f,a6=0.f,a7=0.f;
    int k = 0;
    for (; k + 4 <= cnt; k += 4) {
      int s0 = arow[k], s1 = arow[k+1], s2 = arow[k+2], s3 = arow[k+3];
      uint4 v0 = *(const uint4*)(xb + (size_t)s0 * 64 + jj * 8);
      uint4 v1 = *(const uint4*)(xb + (size_t)s1 * 64 + jj * 8);
      uint4 v2 = *(const uint4*)(xb + (size_t)s2 * 64 + jj * 8);
      uint4 v3 = *(const uint4*)(xb + (size_t)s3 * 64 + jj * 8);
      a0 += bf2f(v0.x & 0xffff) + bf2f(v1.x & 0xffff) + bf2f(v2.x & 0xffff) + bf2f(v3.x & 0xffff);
      a1 += bf2f(v0.x >> 16)    + bf2f(v1.x >> 16)    + bf2f(v2.x >> 16)    + bf2f(v3.x >> 16);
      a2 += bf2f(v0.y & 0xffff) + bf2f(v1.y & 0xffff) + bf2f(v2.y & 0xffff) + bf2f(v3.y & 0xffff);
      a3 += bf2f(v0.y >> 16)    + bf2f(v1.y >> 16)    + bf2f(v2.y >> 16)    + bf2f(v3.y >> 16);
      a4 += bf2f(v0.z & 0xffff) + bf2f(v1.z & 0xffff) + bf2f(v2.z & 0xffff) + bf2f(v3.z & 0xffff);
      a5 += bf2f(v0.z >> 16)    + bf2f(v1.z >> 16)    + bf2f(v2.z >> 16)    + bf2f(v3.z >> 16);
      a6 += bf2f(v0.w & 0xffff) + bf2f(v1.w & 0xffff) + bf2f(v2.w & 0xffff) + bf2f(v3.w & 0xffff);
      a7 += bf2f(v0.w >> 16)    + bf2f(v1.w >> 16)    + bf2f(v2.w >> 16)    + bf2f(v3.w >> 16);
    }
    for (; k < cnt; ++k) {
      int s = arow[k];
      uint4 v = *(const uint4*)(xb + (size_t)s * 64 + jj * 8);
      a0 += bf2f(v.x & 0xffff); a1 += bf2f(v.x >> 16);
      a2 += bf2f(v.y & 0xffff); a3 += bf2f(v.y >> 16);
      a4 += bf2f(v.z & 0xffff); a5 += bf2f(v.z >> 16);
      a6 += bf2f(v.w & 0xffff); a7 += bf2f(v.w >> 16);
    }
    float inv = 1.0f / fmaxf((float)cnt, 1.0f);
    unsigned p0 = ((unsigned)f2bf(a1 * inv) << 16) | f2bf(a0 * inv);
    unsigned p1 = ((unsigned)f2bf(a3 * inv) << 16) | f2bf(a2 * inv);
    unsigned p2 = ((unsigned)f2bf(a5 * inv) << 16) | f2bf(a4 * inv);
    unsigned p3 = ((unsigned)f2bf(a7 * inv) << 16) | f2bf(a6 * inv);
    uint4 pk; pk.x = p0; pk.y = p1; pk.z = p2; pk.w = p3;
    *(uint4*)(astage + nl * 128 + ((jj ^ (nl & 7)) << 4)) = pk;  // slot-swizzled
  }

  // read agg fragments (same-wave ds, slot-swizzled; 2 lanes/bank -> conflict-free)
  const int slr = lr & 7;
  bf16x8 fA0 = *(const bf16x8*)(astage + lr * 128 + ((q ^ slr) << 4));
  bf16x8 fA1 = *(const bf16x8*)(astage + lr * 128 + (((q + 4) ^ slr) << 4));
  bf16x8 fB0 = *(const bf16x8*)(astage + (16 + lr) * 128 + ((q ^ slr) << 4));
  bf16x8 fB1 = *(const bf16x8*)(astage + (16 + lr) * 128 + (((q + 4) ^ slr) << 4));
  __syncthreads();  // agg stage consumed everywhere; w1 staged

  char* ldsA = (char*)&hlds[w][0][0];
  char* ldsB = (char*)&hlds[w][1][0];

  // ---- layer 1: h = relu(acc*SC1 + SH1) -> swizzled h-LDS ----
#pragma unroll
  for (int ot = 0; ot < 8; ++ot) {
    const unsigned short* wp = &wlds[(ot * 4) * 512 + lane * 8];
    bf16x8 w0 = *(const bf16x8*)(wp);
    bf16x8 w1 = *(const bf16x8*)(wp + 512);
    bf16x8 w2 = *(const bf16x8*)(wp + 1024);
    bf16x8 w3 = *(const bf16x8*)(wp + 1536);
    f32x4 aA = {0.f, 0.f, 0.f, 0.f}, aB = {0.f, 0.f, 0.f, 0.f};
    aA = __builtin_amdgcn_mfma_f32_16x16x32_bf16(w0, fA0, aA, 0, 0, 0);
    aA = __builtin_amdgcn_mfma_f32_16x16x32_bf16(w1, fA1, aA, 0, 0, 0);
    aA = __builtin_amdgcn_mfma_f32_16x16x32_bf16(w2, fA2, aA, 0, 0, 0);
    aA = __builtin_amdgcn_mfma_f32_16x16x32_bf16(w3, fA3, aA, 0, 0, 0);
    aB = __builtin_amdgcn_mfma_f32_16x16x32_bf16(w0, fB0, aB, 0, 0, 0);
    aB = __builtin_amdgcn_mfma_f32_16x16x32_bf16(w1, fB1, aB, 0, 0, 0);
    aB = __builtin_amdgcn_mfma_f32_16x16x32_bf16(w2, fB2, aB, 0, 0, 0);
    aB = __builtin_amdgcn_mfma_f32_16x16x32_bf16(w3, fB3, aB, 0, 0, 0);
    const int o = ot * 16 + q * 4;
    float4 sc = *(const float4*)&bnlds[o];
    float4 sh = *(const float4*)&bnlds[128 + o];
    ushort4 hA, hB;
    hA.x = f2bf(fmaxf(aA[0] * sc.x + sh.x, 0.f));
    hA.y = f2bf(fmaxf(aA[1] * sc.y + sh.y, 0.f));
    hA.z = f2bf(fmaxf(aA[2] * sc.z + sh.z, 0.f));
    hA.w = f2bf(fmaxf(aA[3] * sc.w + sh.w, 0.f));
    hB.x = f2bf(fmaxf(aB[0] * sc.x + sh.x, 0.f));
    hB.y = f2bf(fmaxf(aB[1] * sc.y + sh.y, 0.f));
    hB.z = f2bf(fmaxf(aB[2] * sc.z + sh.z, 0.f));
    hB.w = f2bf(fmaxf(aB[3] * sc.w + sh.w, 0.f));
    const int wb = lr * 256 + ot * 32 + q * 8;
    *(ushort4*)(ldsA + (wb ^ swz)) = hA;
    *(ushort4*)(ldsB + (wb ^ swz)) = hB;
  }
  __syncthreads();

  // stage w2 into the same LDS
  for (int idx = tid; idx < 2048; idx += 256) {
    int f = idx >> 6, l = idx & 63;
    int gofs = ((f >> 2) * 16 + (l & 15)) * 128 + (f & 3) * 32 + (l >> 4) * 8;
    *(uint4*)&wlds[idx * 8] = *(const uint4*)&w2c[gofs];
  }
  __syncthreads();

  // read back h as B-fragments
  bf16x8 hA[4], hB[4];
#pragma unroll
  for (int jx = 0; jx < 4; ++jx) {
    const int rb = lr * 256 + jx * 64 + q * 16;
    hA[jx] = *(const bf16x8*)(ldsA + (rb ^ swz));
    hB[jx] = *(const bf16x8*)(ldsB + (rb ^ swz));
  }

  // ---- layer 2: ot<4 -> t (bf16), ot>=4 -> r2 (bf16, bias folded into BN2) ----
#pragma unroll
  for (int ot = 0; ot < 8; ++ot) {
    const unsigned short* wp = &wlds[(ot * 4) * 512 + lane * 8];
    bf16x8 w0 = *(const bf16x8*)(wp);
    bf16x8 w1 = *(const bf16x8*)(wp + 512);
    bf16x8 w2 = *(const bf16x8*)(wp + 1024);
    bf16x8 w3 = *(const bf16x8*)(wp + 1536);
    f32x4 aA = {0.f, 0.f, 0.f, 0.f}, aB = {0.f, 0.f, 0.f, 0.f};
    aA = __builtin_amdgcn_mfma_f32_16x16x32_bf16(w0, hA[0], aA, 0, 0, 0);
    aA = __builtin_amdgcn_mfma_f32_16x16x32_bf16(w1, hA[1], aA, 0, 0, 0);
    aA = __builtin_amdgcn_mfma_f32_16x16x32_bf16(w2, hA[2], aA, 0, 0, 0);
    aA = __builtin_amdgcn_mfma_f32_16x16x32_bf16(w3, hA[3], aA, 0, 0, 0);
    aB = __builtin_amdgcn_mfma_f32_16x16x32_bf16(w0, hB[0], aB, 0, 0, 0);
    aB = __builtin_amdgcn_mfma_f32_16x16x32_bf16(w1, hB[1], aB, 0, 0, 0);
    aB = __builtin_amdgcn_mfma_f32_16x16x32_bf16(w2, hB[2], aB, 0, 0, 0);
    aB = __builtin_amdgcn_mfma_f32_16x16x32_bf16(w3, hB[3], aB, 0, 0, 0);
    ushort4 tv;
    if (ot < 4) {
      const int o = ot * 16 + q * 4;
      tv.x = f2bf(aA[0]); tv.y = f2bf(aA[1]); tv.z = f2bf(aA[2]); tv.w = f2bf(aA[3]);
      if (nA < NN) *(ushort4*)(t + (size_t)nA * 64 + o) = tv;
      tv.x = f2bf(aB[0]); tv.y = f2bf(aB[1]); tv.z = f2bf(aB[2]); tv.w = f2bf(aB[3]);
      if (nB < NN) *(ushort4*)(t + (size_t)nB * 64 + o) = tv;
    } else {
      const int o = (ot - 4) * 16 + q * 4;
      tv.x = f2bf(aA[0]); tv.y = f2bf(aA[1]); tv.z = f2bf(aA[2]); tv.w = f2bf(aA[3]);
      if (nA < NN) *(ushort4*)(r2 + (size_t)nA * 64 + o) = tv;
      tv.x = f2bf(aB[0]); tv.y = f2bf(aB[1]); tv.z = f2bf(aB[2]); tv.w = f2bf(aB[3]);
      if (nB < NN) *(ushort4*)(r2 + (size_t)nB * 64 + o) = tv;
    }
  }
}

// ---------------- layer2 aggregate (bf16 t) + bf16 r2 + BN2: 8 lanes/node ----------------
__global__ __launch_bounds__(256) void k_agg2fin(const unsigned short* __restrict__ t,
                                                 const int* __restrict__ deg,
                                                 const int* __restrict__ offset,
                                                 const int* __restrict__ csr,
                                                 const unsigned short* __restrict__ r2,
                                                 const float* __restrict__ bn,
                                                 float* __restrict__ outp) {
  int tid = threadIdx.x;
  int node = blockIdx.x * 32 + (tid >> 3);
  int j = tid & 7;
  int cnt = deg[node];
  const int* arow = csr + offset[node];
  float a0=0.f,a1=0.f,a2=0.f,a3=0.f,a4=0.f,a5=0.f,a6=0.f,a7=0.f;
  int k = 0;
  for (; k + 4 <= cnt; k += 4) {
    int s0 = arow[k], s1 = arow[k+1], s2 = arow[k+2], s3 = arow[k+3];
    uint4 v0 = *(const uint4*)(t + (size_t)s0 * 64 + j * 8);
    uint4 v1 = *(const uint4*)(t + (size_t)s1 * 64 + j * 8);
    uint4 v2 = *(const uint4*)(t + (size_t)s2 * 64 + j * 8);
    uint4 v3 = *(const uint4*)(t + (size_t)s3 * 64 + j * 8);
    a0 += bf2f(v0.x & 0xffff) + bf2f(v1.x & 0xffff) + bf2f(v2.x & 0xffff) + bf2f(v3.x & 0xffff);
    a1 += bf2f(v0.x >> 16)    + bf2f(v1.x >> 16)    + bf2f(v2.x >> 16)    + bf2f(v3.x >> 16);
    a2 += bf2f(v0.y & 0xffff) + bf2f(v1.y & 0xffff) + bf2f(v2.y & 0xffff) + bf2f(v3.y & 0xffff);
    a3 += bf2f(v0.y >> 16)    + bf2f(v1.y >> 16)    + bf2f(v2.y >> 16)    + bf2f(v3.y >> 16);
    a4 += bf2f(v0.z & 0xffff) + bf2f(v1.z & 0xffff) + bf2f(v2.z & 0xffff) + bf2f(v3.z & 0xffff);
    a5 += bf2f(v0.z >> 16)    + bf2f(v1.z >> 16)    + bf2f(v2.z >> 16)    + bf2f(v3.z >> 16);
    a6 += bf2f(v0.w & 0xffff) + bf2f(v1.w & 0xffff) + bf2f(v2.w & 0xffff) + bf2f(v3.w & 0xffff);
    a7 += bf2f(v0.w >> 16)    + bf2f(v1.w >> 16)    + bf2f(v2.w >> 16)    + bf2f(v3.w >> 16);
  }
  for (; k < cnt; ++k) {
    int s = arow[k];
    uint4 v = *(const uint4*)(t + (size_t)s * 64 + j * 8);
    a0 += bf2f(v.x & 0xffff); a1 += bf2f(v.x >> 16);
    a2 += bf2f(v.y & 0xffff); a3 += bf2f(v.y >> 16);
    a4 += bf2f(v.z & 0xffff); a5 += bf2f(v.z >> 16);
    a6 += bf2f(v.w & 0xffff); a7 += bf2f(v.w >> 16);
  }
  float inv = 1.0f / fmaxf((float)cnt, 1.0f);
  int o = j * 8;
  uint4 rv = *(const uint4*)(r2 + (size_t)node * 64 + o);
  float r0 = bf2f(rv.x & 0xffff), r1 = bf2f(rv.x >> 16);
  float r2a = bf2f(rv.y & 0xffff), r3 = bf2f(rv.y >> 16);
  float r4 = bf2f(rv.z & 0xffff), r5 = bf2f(rv.z >> 16);
  float r6 = bf2f(rv.w & 0xffff), r7 = bf2f(rv.w >> 16);
  float4 sca = *(const float4*)(bn + 256 + o);
  float4 scb = *(const float4*)(bn + 256 + o + 4);
  float4 sha = *(const float4*)(bn + 320 + o);
  float4 shb = *(const float4*)(bn + 320 + o + 4);
  float4 o0, o1;
  o0.x = (a0 * inv + r0) * sca.x + sha.x;
  o0.y = (a1 * inv + r1) * sca.y + sha.y;
  o0.z = (a2 * inv + r2a) * sca.z + sha.z;
  o0.w = (a3 * inv + r3) * sca.w + sha.w;
  o1.x = (a4 * inv + r4) * scb.x + shb.x;
  o1.y = (a5 * inv + r5) * scb.y + shb.y;
  o1.z = (a6 * inv + r6) * scb.z + shb.z;
  o1.w = (a7 * inv + r7) * scb.w + shb.w;
  *(float4*)(outp + (size_t)node * 64 + o) = o0;
  *(float4*)(outp + (size_t)node * 64 + o + 4) = o1;
}

extern "C" void kernel_launch(void* const* d_in, const int* in_sizes, int n_in,
                              void* d_out, int out_size, void* d_ws, size_t ws_size,
                              hipStream_t stream) {
  const float* x   = (const float*)d_in[0];
  const int*   ei  = (const int*)d_in[1];
  const float* w1l = (const float*)d_in[2];
  const float* b1l = (const float*)d_in[3];
  const float* w1r = (const float*)d_in[4];
  const float* g1  = (const float*)d_in[5];
  const float* be1 = (const float*)d_in[6];
  const float* m1  = (const float*)d_in[7];
  const float* v1  = (const float*)d_in[8];
  const float* w2l = (const float*)d_in[9];
  const float* b2l = (const float*)d_in[10];
  const float* w2r = (const float*)d_in[11];
  const float* g2  = (const float*)d_in[12];
  const float* be2 = (const float*)d_in[13];
  const float* m2  = (const float*)d_in[14];
  const float* v2  = (const float*)d_in[15];
  float* outp = (float*)d_out;

  char* ws = (char*)d_ws;
  // layout (bytes), 16B-aligned:
  //           0 : gcur       (2,048)
  //       2,048 : bucketBase (2,048)
  //       4,096 : deg        (400,000)     -> 404,096
  //     404,096 : offset     (400,000)     -> 804,096
  //     804,096 : pairs      (7,206,912)   -> 8,011,008   (391*4608*4)
  //   8,011,008 : csr        (6,400,000)   -> 14,411,008
  //  14,411,008 : w1c bf16   (32,768)      -> 14,443,776
  //  14,443,776 : w2c bf16   (32,768)      -> 14,476,544
  //  14,476,544 : bn  fp32   (2,048)       -> 14,478,592
  //  14,478,592 : xb  bf16   (12,800,000)  -> 27,278,592
  //  27,278,592 : t   bf16   (12,800,000)  -> 40,078,592
  //  40,078,592 : r2  bf16   (12,800,000)  -> 52,878,592  (~53 MB)
  int*            gcur       = (int*)ws;
  int*            bucketBase = (int*)(ws + 2048);
  int*            deg        = (int*)(ws + 4096);
  int*            offset     = (int*)(ws + 404096);
  unsigned*       pairs      = (unsigned*)(ws + 804096);
  int*            csr        = (int*)(ws + 8011008);
  unsigned short* w1c        = (unsigned short*)(ws + 14411008);
  unsigned short* w2c        = (unsigned short*)(ws + 14443776);
  float*          bn         = (float*)(ws + 14476544);
  unsigned short* xb         = (unsigned short*)(ws + 14478592);
  unsigned short* t          = (unsigned short*)(ws + 27278592);
  unsigned short* r2         = (unsigned short*)(ws + 40078592);

  const int* srcp = ei;
  const int* dstp = ei + NE;

  hipMemsetAsync(gcur, 0, NBUK * sizeof(int), stream);
  hipLaunchKernelGGL(k_bin, dim3(NTIL), dim3(256), 0, stream,
                     srcp, dstp, gcur, pairs);
  hipLaunchKernelGGL(k_bscan, dim3(1), dim3(256), 0, stream, gcur, bucketBase);
  hipLaunchKernelGGL(k_build, dim3(NBUK), dim3(512), 0, stream,
                     pairs, gcur, bucketBase, deg, offset, csr);
  hipLaunchKernelGGL(k_wprep, dim3(64), dim3(256), 0, stream,
                     w1l, w1r, w2l, w2r, b1l, g1, be1, m1, v1,
                     b2l, g2, be2, m2, v2, w1c, w2c, bn);
  hipLaunchKernelGGL(k_cvtx, dim3(NN * 64 / 1024), dim3(256), 0, stream, x, xb);
  hipLaunchKernelGGL(k_aggemm, dim3((NN + 127) / 128), dim3(256), 0, stream,
                     xb, deg, offset, csr, w1c, w2c, bn, t, r2);
  hipLaunchKernelGGL(k_agg2fin, dim3(NN / 32), dim3(256), 0, stream,
                     t, deg, offset, csr, r2, bn, outp);
}

// Round 12
// 166.300 us; speedup vs baseline: 1.0974x; 1.0974x over previous
//
#include <hip/hip_runtime.h>

#define NN 100000
#define NE 1600000
#define EPSV 1e-5f

#define NBUK 391       // buckets of 256 nodes: bucket = dst >> 8
#define TILE 2048      // edges per k_bin workgroup
#define NTIL 782       // ceil(NE / TILE)
#define CAP  4608      // per-bucket capacity (mean 4092, sigma ~64 -> +8 sigma)

typedef __attribute__((ext_vector_type(8))) short bf16x8;
typedef __attribute__((ext_vector_type(4))) float f32x4;

__device__ inline unsigned short f2bf(float f) {
  unsigned u = __builtin_bit_cast(unsigned, f);
  unsigned r = u + 0x7FFFu + ((u >> 16) & 1u);
  return (unsigned short)(r >> 16);
}
__device__ inline float bf2f(unsigned short s) {
  unsigned u = ((unsigned)s) << 16;
  return __builtin_bit_cast(float, u);
}

// ---------------- phase 1: LDS-binned edge partition ----------------
__global__ __launch_bounds__(256) void k_bin(const int* __restrict__ src,
                                             const int* __restrict__ dst,
                                             int* __restrict__ gcur,
                                             unsigned* __restrict__ pairs) {
  __shared__ int cnt[NBUK];
  __shared__ int lo[NBUK];
  __shared__ int gbase[NBUK];
  __shared__ int ts[256];
  __shared__ unsigned stage[TILE];
  const int tid = threadIdx.x;
  const int e0 = blockIdx.x * TILE;
  const int m = min(TILE, NE - e0);

  for (int i = tid; i < NBUK; i += 256) cnt[i] = 0;
  __syncthreads();
  for (int i = tid; i < m; i += 256) {
    int d = dst[e0 + i];
    atomicAdd(&cnt[d >> 8], 1);
  }
  __syncthreads();
  const int i0 = 2 * tid, i1 = 2 * tid + 1;
  int c0 = (i0 < NBUK) ? cnt[i0] : 0;
  int c1 = (i1 < NBUK) ? cnt[i1] : 0;
  int s2 = c0 + c1;
  ts[tid] = s2;
  __syncthreads();
  for (int d = 1; d < 256; d <<= 1) {
    int v = (tid >= d) ? ts[tid - d] : 0;
    __syncthreads();
    ts[tid] += v;
    __syncthreads();
  }
  int ex = ts[tid] - s2;
  if (i0 < NBUK) { lo[i0] = ex;      gbase[i0] = atomicAdd(&gcur[i0], c0); }
  if (i1 < NBUK) { lo[i1] = ex + c0; gbase[i1] = atomicAdd(&gcur[i1], c1); }
  __syncthreads();
  if (i0 < NBUK) cnt[i0] = lo[i0];
  if (i1 < NBUK) cnt[i1] = lo[i1];
  __syncthreads();
  for (int i = tid; i < m; i += 256) {
    int d = dst[e0 + i];
    int s = src[e0 + i];
    int b = d >> 8;
    int pos = atomicAdd(&cnt[b], 1);
    stage[pos] = ((unsigned)(d & 255) << 17) | (unsigned)s;
  }
  __syncthreads();
  for (int i = tid; i < m; i += 256) {
    int a = 0, z = NBUK - 1;
    while (a < z) {
      int mid = (a + z + 1) >> 1;
      if (lo[mid] <= i) a = mid; else z = mid - 1;
    }
    int rel = gbase[a] + (i - lo[a]);
    if (rel < CAP) pairs[(size_t)a * CAP + rel] = stage[i];
  }
}

// ---------------- phase 1.5: scan bucket counts ----------------
__global__ __launch_bounds__(256) void k_bscan(const int* __restrict__ gcur,
                                               int* __restrict__ bucketBase) {
  __shared__ int ts[256];
  const int tid = threadIdx.x;
  const int i0 = 2 * tid, i1 = 2 * tid + 1;
  int c0 = (i0 < NBUK) ? min(gcur[i0], CAP) : 0;
  int c1 = (i1 < NBUK) ? min(gcur[i1], CAP) : 0;
  int s2 = c0 + c1;
  ts[tid] = s2;
  __syncthreads();
  for (int d = 1; d < 256; d <<= 1) {
    int v = (tid >= d) ? ts[tid - d] : 0;
    __syncthreads();
    ts[tid] += v;
    __syncthreads();
  }
  int ex = ts[tid] - s2;
  if (i0 < NBUK) bucketBase[i0] = ex;
  if (i1 < NBUK) bucketBase[i1] = ex + c0;
}

// ---------------- phase 2: per-bucket CSR build (512 threads, 391 blocks) ----------------
__global__ __launch_bounds__(512) void k_build(const unsigned* __restrict__ pairs,
                                               const int* __restrict__ gcur,
                                               const int* __restrict__ bucketBase,
                                               int* __restrict__ deg,
                                               int* __restrict__ offset,
                                               int* __restrict__ csr) {
  __shared__ int hist[256];
  __shared__ int ts[256];
  __shared__ unsigned stage[CAP];
  const int tid = threadIdx.x;
  const int b = blockIdx.x;
  const int count = min(gcur[b], CAP);
  const int nbase = b * 256;
  const int nloc = min(256, NN - nbase);
  const unsigned* pb = pairs + (size_t)b * CAP;
  const int obase = bucketBase[b];

  if (tid < 256) hist[tid] = 0;
  __syncthreads();
  for (int i = tid; i < count; i += 512) {
    atomicAdd(&hist[pb[i] >> 17], 1);
  }
  __syncthreads();
  int s = 0;
  if (tid < 256) { s = hist[tid]; ts[tid] = s; }
  __syncthreads();
  for (int d = 1; d < 256; d <<= 1) {
    int v = 0;
    if (tid < 256 && tid >= d) v = ts[tid - d];
    __syncthreads();
    if (tid < 256) ts[tid] += v;
    __syncthreads();
  }
  if (tid < 256) {
    int ex = ts[tid] - s;
    if (tid < nloc) {
      deg[nbase + tid] = s;
      offset[nbase + tid] = obase + ex;
    }
    hist[tid] = ex;  // cursor
  }
  __syncthreads();
  for (int i = tid; i < count; i += 512) {
    unsigned e = pb[i];
    int pos = atomicAdd(&hist[e >> 17], 1);
    stage[pos] = e & 0x1FFFFu;
  }
  __syncthreads();
  for (int i = tid; i < count; i += 512) csr[obase + i] = (int)stage[i];
}

// ---------------- weight + BN-param prep ----------------
__global__ __launch_bounds__(256) void k_wprep(const float* __restrict__ w1l,
                                               const float* __restrict__ w1r,
                                               const float* __restrict__ w2l,
                                               const float* __restrict__ w2r,
                                               const float* __restrict__ b1l,
                                               const float* __restrict__ g1,
                                               const float* __restrict__ be1,
                                               const float* __restrict__ m1,
                                               const float* __restrict__ v1,
                                               const float* __restrict__ b2l,
                                               const float* __restrict__ g2,
                                               const float* __restrict__ be2,
                                               const float* __restrict__ m2,
                                               const float* __restrict__ v2,
                                               unsigned short* __restrict__ w1c,
                                               unsigned short* __restrict__ w2c,
                                               float* __restrict__ bn) {
  int i = blockIdx.x * 256 + threadIdx.x;  // 0..16383
  int o = i >> 7, k = i & 127;
  float vv1 = (k < 64) ? w1l[o * 64 + k] : w1r[o * 64 + (k - 64)];
  w1c[i] = f2bf(vv1);
  float vv2 = (o < 64) ? w2l[o * 128 + k] : w2r[(o - 64) * 128 + k];
  w2c[i] = f2bf(vv2);
  if (i < 128) {
    float sc = g1[i] * rsqrtf(v1[i] + EPSV);
    bn[i] = sc;
    bn[128 + i] = (b1l[i] - m1[i]) * sc + be1[i];
  }
  if (i < 64) {
    float sc = g2[i] * rsqrtf(v2[i] + EPSV);
    bn[256 + i] = sc;
    bn[320 + i] = (b2l[i] - m2[i]) * sc + be2[i];
  }
}

// ---------------- convert x -> bf16 ----------------
__global__ __launch_bounds__(256) void k_cvtx(const float* __restrict__ x,
                                              unsigned short* __restrict__ xb) {
  int i = blockIdx.x * 256 + threadIdx.x;
  float4 v = *(const float4*)(x + (size_t)i * 4);
  ushort4 o;
  o.x = f2bf(v.x); o.y = f2bf(v.y); o.z = f2bf(v.z); o.w = f2bf(v.w);
  *(ushort4*)(xb + (size_t)i * 4) = o;
}

// ---------------- mean-aggregate: 8 lanes/node, 16B per lane ----------------
__global__ __launch_bounds__(256) void k_aggregate(const unsigned short* __restrict__ xb,
                                                   const int* __restrict__ deg,
                                                   const int* __restrict__ offset,
                                                   const int* __restrict__ csr,
                                                   unsigned short* __restrict__ aggB) {
  int tid = threadIdx.x;
  int node = blockIdx.x * 32 + (tid >> 3);
  int j = tid & 7;
  int cnt = deg[node];
  const int* arow = csr + offset[node];
  float a0=0.f,a1=0.f,a2=0.f,a3=0.f,a4=0.f,a5=0.f,a6=0.f,a7=0.f;
  int k = 0;
  for (; k + 4 <= cnt; k += 4) {
    int s0 = arow[k], s1 = arow[k+1], s2 = arow[k+2], s3 = arow[k+3];
    uint4 v0 = *(const uint4*)(xb + (size_t)s0 * 64 + j * 8);
    uint4 v1 = *(const uint4*)(xb + (size_t)s1 * 64 + j * 8);
    uint4 v2 = *(const uint4*)(xb + (size_t)s2 * 64 + j * 8);
    uint4 v3 = *(const uint4*)(xb + (size_t)s3 * 64 + j * 8);
    a0 += bf2f(v0.x & 0xffff) + bf2f(v1.x & 0xffff) + bf2f(v2.x & 0xffff) + bf2f(v3.x & 0xffff);
    a1 += bf2f(v0.x >> 16)    + bf2f(v1.x >> 16)    + bf2f(v2.x >> 16)    + bf2f(v3.x >> 16);
    a2 += bf2f(v0.y & 0xffff) + bf2f(v1.y & 0xffff) + bf2f(v2.y & 0xffff) + bf2f(v3.y & 0xffff);
    a3 += bf2f(v0.y >> 16)    + bf2f(v1.y >> 16)    + bf2f(v2.y >> 16)    + bf2f(v3.y >> 16);
    a4 += bf2f(v0.z & 0xffff) + bf2f(v1.z & 0xffff) + bf2f(v2.z & 0xffff) + bf2f(v3.z & 0xffff);
    a5 += bf2f(v0.z >> 16)    + bf2f(v1.z >> 16)    + bf2f(v2.z >> 16)    + bf2f(v3.z >> 16);
    a6 += bf2f(v0.w & 0xffff) + bf2f(v1.w & 0xffff) + bf2f(v2.w & 0xffff) + bf2f(v3.w & 0xffff);
    a7 += bf2f(v0.w >> 16)    + bf2f(v1.w >> 16)    + bf2f(v2.w >> 16)    + bf2f(v3.w >> 16);
  }
  for (; k < cnt; ++k) {
    int s = arow[k];
    uint4 v = *(const uint4*)(xb + (size_t)s * 64 + j * 8);
    a0 += bf2f(v.x & 0xffff); a1 += bf2f(v.x >> 16);
    a2 += bf2f(v.y & 0xffff); a3 += bf2f(v.y >> 16);
    a4 += bf2f(v.z & 0xffff); a5 += bf2f(v.z >> 16);
    a6 += bf2f(v.w & 0xffff); a7 += bf2f(v.w >> 16);
  }
  float inv = 1.0f / fmaxf((float)cnt, 1.0f);
  ushort4 r0, r1;
  r0.x = f2bf(a0 * inv); r0.y = f2bf(a1 * inv); r0.z = f2bf(a2 * inv); r0.w = f2bf(a3 * inv);
  r1.x = f2bf(a4 * inv); r1.y = f2bf(a5 * inv); r1.z = f2bf(a6 * inv); r1.w = f2bf(a7 * inv);
  *(ushort4*)(aggB + (size_t)node * 64 + j * 8) = r0;
  *(ushort4*)(aggB + (size_t)node * 64 + j * 8 + 4) = r1;
}

// ---------------- fused MFMA: all in-loop operands from LDS ----------------
// 4 waves/block, 32 nodes/wave. LDS: 32KB weights (time-muxed) + 32KB h + 1.5KB bn
// = ~66KB -> 2 blocks/CU. The ot loops contain zero global loads.
__global__ __launch_bounds__(256) void k_gemm12(const unsigned short* __restrict__ aggB,
                                                const unsigned short* __restrict__ xb,
                                                const unsigned short* __restrict__ w1c,
                                                const unsigned short* __restrict__ w2c,
                                                const float* __restrict__ bn,
                                                unsigned short* __restrict__ t,
                                                unsigned short* __restrict__ r2) {
  __shared__ unsigned short wlds[32 * 512];       // 32KB: frag f at f*512, lane*8
  __shared__ unsigned short hlds[4][2][16 * 128]; // 32KB
  __shared__ float bnlds[384];                    // 1.5KB
  const int tid = threadIdx.x;
  const int w = tid >> 6;
  const int lane = tid & 63;
  const int lr = lane & 15;
  const int q = lane >> 4;
  const int base = blockIdx.x * 128 + w * 32;
  const int nA = base + lr, nB = base + 16 + lr;
  const int cA = min(nA, NN - 1), cB = min(nB, NN - 1);
  const int swz = (lr & 7) << 4;

  // issue activation loads first (latency hides under staging + barrier)
  bf16x8 fA[4], fB[4];
  {
    const unsigned short* a = aggB + (size_t)cA * 64 + q * 8;
    const unsigned short* xx = xb + (size_t)cA * 64 + q * 8;
    fA[0] = *(const bf16x8*)a;        fA[1] = *(const bf16x8*)(a + 32);
    fA[2] = *(const bf16x8*)xx;       fA[3] = *(const bf16x8*)(xx + 32);
  }
  {
    const unsigned short* a = aggB + (size_t)cB * 64 + q * 8;
    const unsigned short* xx = xb + (size_t)cB * 64 + q * 8;
    fB[0] = *(const bf16x8*)a;        fB[1] = *(const bf16x8*)(a + 32);
    fB[2] = *(const bf16x8*)xx;       fB[3] = *(const bf16x8*)(xx + 32);
  }

  // stage bn + w1 (fragment-major)
  for (int i = tid; i < 384; i += 256) bnlds[i] = bn[i];
  for (int idx = tid; idx < 2048; idx += 256) {
    int f = idx >> 6, l = idx & 63;
    int gofs = ((f >> 2) * 16 + (l & 15)) * 128 + (f & 3) * 32 + (l >> 4) * 8;
    *(uint4*)&wlds[idx * 8] = *(const uint4*)&w1c[gofs];
  }
  __syncthreads();

  char* ldsA = (char*)&hlds[w][0][0];
  char* ldsB = (char*)&hlds[w][1][0];

  // ---- layer 1 ----
#pragma unroll
  for (int ot = 0; ot < 8; ++ot) {
    const unsigned short* wp = &wlds[(ot * 4) * 512 + lane * 8];
    bf16x8 w0 = *(const bf16x8*)(wp);
    bf16x8 w1 = *(const bf16x8*)(wp + 512);
    bf16x8 w2 = *(const bf16x8*)(wp + 1024);
    bf16x8 w3 = *(const bf16x8*)(wp + 1536);
    f32x4 aA = {0.f, 0.f, 0.f, 0.f}, aB = {0.f, 0.f, 0.f, 0.f};
    aA = __builtin_amdgcn_mfma_f32_16x16x32_bf16(w0, fA[0], aA, 0, 0, 0);
    aA = __builtin_amdgcn_mfma_f32_16x16x32_bf16(w1, fA[1], aA, 0, 0, 0);
    aA = __builtin_amdgcn_mfma_f32_16x16x32_bf16(w2, fA[2], aA, 0, 0, 0);
    aA = __builtin_amdgcn_mfma_f32_16x16x32_bf16(w3, fA[3], aA, 0, 0, 0);
    aB = __builtin_amdgcn_mfma_f32_16x16x32_bf16(w0, fB[0], aB, 0, 0, 0);
    aB = __builtin_amdgcn_mfma_f32_16x16x32_bf16(w1, fB[1], aB, 0, 0, 0);
    aB = __builtin_amdgcn_mfma_f32_16x16x32_bf16(w2, fB[2], aB, 0, 0, 0);
    aB = __builtin_amdgcn_mfma_f32_16x16x32_bf16(w3, fB[3], aB, 0, 0, 0);
    const int o = ot * 16 + q * 4;
    float4 sc = *(const float4*)&bnlds[o];
    float4 sh = *(const float4*)&bnlds[128 + o];
    ushort4 hA, hB;
    hA.x = f2bf(fmaxf(aA[0] * sc.x + sh.x, 0.f));
    hA.y = f2bf(fmaxf(aA[1] * sc.y + sh.y, 0.f));
    hA.z = f2bf(fmaxf(aA[2] * sc.z + sh.z, 0.f));
    hA.w = f2bf(fmaxf(aA[3] * sc.w + sh.w, 0.f));
    hB.x = f2bf(fmaxf(aB[0] * sc.x + sh.x, 0.f));
    hB.y = f2bf(fmaxf(aB[1] * sc.y + sh.y, 0.f));
    hB.z = f2bf(fmaxf(aB[2] * sc.z + sh.z, 0.f));
    hB.w = f2bf(fmaxf(aB[3] * sc.w + sh.w, 0.f));
    const int wb = lr * 256 + ot * 32 + q * 8;
    *(ushort4*)(ldsA + (wb ^ swz)) = hA;
    *(ushort4*)(ldsB + (wb ^ swz)) = hB;
  }
  __syncthreads();

  // stage w2 into the same LDS
  for (int idx = tid; idx < 2048; idx += 256) {
    int f = idx >> 6, l = idx & 63;
    int gofs = ((f >> 2) * 16 + (l & 15)) * 128 + (f & 3) * 32 + (l >> 4) * 8;
    *(uint4*)&wlds[idx * 8] = *(const uint4*)&w2c[gofs];
  }
  __syncthreads();

  // read back h as B-fragments
  bf16x8 hA[4], hB[4];
#pragma unroll
  for (int jj = 0; jj < 4; ++jj) {
    const int rb = lr * 256 + jj * 64 + q * 16;
    hA[jj] = *(const bf16x8*)(ldsA + (rb ^ swz));
    hB[jj] = *(const bf16x8*)(ldsB + (rb ^ swz));
  }

  // ---- layer 2: ot<4 -> t (bf16), ot>=4 -> r2 (bf16, bias folded into BN2) ----
#pragma unroll
  for (int ot = 0; ot < 8; ++ot) {
    const unsigned short* wp = &wlds[(ot * 4) * 512 + lane * 8];
    bf16x8 w0 = *(const bf16x8*)(wp);
    bf16x8 w1 = *(const bf16x8*)(wp + 512);
    bf16x8 w2 = *(const bf16x8*)(wp + 1024);
    bf16x8 w3 = *(const bf16x8*)(wp + 1536);
    f32x4 aA = {0.f, 0.f, 0.f, 0.f}, aB = {0.f, 0.f, 0.f, 0.f};
    aA = __builtin_amdgcn_mfma_f32_16x16x32_bf16(w0, hA[0], aA, 0, 0, 0);
    aA = __builtin_amdgcn_mfma_f32_16x16x32_bf16(w1, hA[1], aA, 0, 0, 0);
    aA = __builtin_amdgcn_mfma_f32_16x16x32_bf16(w2, hA[2], aA, 0, 0, 0);
    aA = __builtin_amdgcn_mfma_f32_16x16x32_bf16(w3, hA[3], aA, 0, 0, 0);
    aB = __builtin_amdgcn_mfma_f32_16x16x32_bf16(w0, hB[0], aB, 0, 0, 0);
    aB = __builtin_amdgcn_mfma_f32_16x16x32_bf16(w1, hB[1], aB, 0, 0, 0);
    aB = __builtin_amdgcn_mfma_f32_16x16x32_bf16(w2, hB[2], aB, 0, 0, 0);
    aB = __builtin_amdgcn_mfma_f32_16x16x32_bf16(w3, hB[3], aB, 0, 0, 0);
    ushort4 tv;
    if (ot < 4) {
      const int o = ot * 16 + q * 4;
      tv.x = f2bf(aA[0]); tv.y = f2bf(aA[1]); tv.z = f2bf(aA[2]); tv.w = f2bf(aA[3]);
      if (nA < NN) *(ushort4*)(t + (size_t)nA * 64 + o) = tv;
      tv.x = f2bf(aB[0]); tv.y = f2bf(aB[1]); tv.z = f2bf(aB[2]); tv.w = f2bf(aB[3]);
      if (nB < NN) *(ushort4*)(t + (size_t)nB * 64 + o) = tv;
    } else {
      const int o = (ot - 4) * 16 + q * 4;
      tv.x = f2bf(aA[0]); tv.y = f2bf(aA[1]); tv.z = f2bf(aA[2]); tv.w = f2bf(aA[3]);
      if (nA < NN) *(ushort4*)(r2 + (size_t)nA * 64 + o) = tv;
      tv.x = f2bf(aB[0]); tv.y = f2bf(aB[1]); tv.z = f2bf(aB[2]); tv.w = f2bf(aB[3]);
      if (nB < NN) *(ushort4*)(r2 + (size_t)nB * 64 + o) = tv;
    }
  }
}

// ---------------- layer2 aggregate (bf16 t) + bf16 r2 + BN2: 8 lanes/node ----------------
__global__ __launch_bounds__(256) void k_agg2fin(const unsigned short* __restrict__ t,
                                                 const int* __restrict__ deg,
                                                 const int* __restrict__ offset,
                                                 const int* __restrict__ csr,
                                                 const unsigned short* __restrict__ r2,
                                                 const float* __restrict__ bn,
                                                 float* __restrict__ outp) {
  int tid = threadIdx.x;
  int node = blockIdx.x * 32 + (tid >> 3);
  int j = tid & 7;
  int cnt = deg[node];
  const int* arow = csr + offset[node];
  float a0=0.f,a1=0.f,a2=0.f,a3=0.f,a4=0.f,a5=0.f,a6=0.f,a7=0.f;
  int k = 0;
  for (; k + 4 <= cnt; k += 4) {
    int s0 = arow[k], s1 = arow[k+1], s2 = arow[k+2], s3 = arow[k+3];
    uint4 v0 = *(const uint4*)(t + (size_t)s0 * 64 + j * 8);
    uint4 v1 = *(const uint4*)(t + (size_t)s1 * 64 + j * 8);
    uint4 v2 = *(const uint4*)(t + (size_t)s2 * 64 + j * 8);
    uint4 v3 = *(const uint4*)(t + (size_t)s3 * 64 + j * 8);
    a0 += bf2f(v0.x & 0xffff) + bf2f(v1.x & 0xffff) + bf2f(v2.x & 0xffff) + bf2f(v3.x & 0xffff);
    a1 += bf2f(v0.x >> 16)    + bf2f(v1.x >> 16)    + bf2f(v2.x >> 16)    + bf2f(v3.x >> 16);
    a2 += bf2f(v0.y & 0xffff) + bf2f(v1.y & 0xffff) + bf2f(v2.y & 0xffff) + bf2f(v3.y & 0xffff);
    a3 += bf2f(v0.y >> 16)    + bf2f(v1.y >> 16)    + bf2f(v2.y >> 16)    + bf2f(v3.y >> 16);
    a4 += bf2f(v0.z & 0xffff) + bf2f(v1.z & 0xffff) + bf2f(v2.z & 0xffff) + bf2f(v3.z & 0xffff);
    a5 += bf2f(v0.z >> 16)    + bf2f(v1.z >> 16)    + bf2f(v2.z >> 16)    + bf2f(v3.z >> 16);
    a6 += bf2f(v0.w & 0xffff) + bf2f(v1.w & 0xffff) + bf2f(v2.w & 0xffff) + bf2f(v3.w & 0xffff);
    a7 += bf2f(v0.w >> 16)    + bf2f(v1.w >> 16)    + bf2f(v2.w >> 16)    + bf2f(v3.w >> 16);
  }
  for (; k < cnt; ++k) {
    int s = arow[k];
    uint4 v = *(const uint4*)(t + (size_t)s * 64 + j * 8);
    a0 += bf2f(v.x & 0xffff); a1 += bf2f(v.x >> 16);
    a2 += bf2f(v.y & 0xffff); a3 += bf2f(v.y >> 16);
    a4 += bf2f(v.z & 0xffff); a5 += bf2f(v.z >> 16);
    a6 += bf2f(v.w & 0xffff); a7 += bf2f(v.w >> 16);
  }
  float inv = 1.0f / fmaxf((float)cnt, 1.0f);
  int o = j * 8;
  uint4 rv = *(const uint4*)(r2 + (size_t)node * 64 + o);
  float r0 = bf2f(rv.x & 0xffff), r1 = bf2f(rv.x >> 16);
  float r2a = bf2f(rv.y & 0xffff), r3 = bf2f(rv.y >> 16);
  float r4 = bf2f(rv.z & 0xffff), r5 = bf2f(rv.z >> 16);
  float r6 = bf2f(rv.w & 0xffff), r7 = bf2f(rv.w >> 16);
  float4 sca = *(const float4*)(bn + 256 + o);
  float4 scb = *(const float4*)(bn + 256 + o + 4);
  float4 sha = *(const float4*)(bn + 320 + o);
  float4 shb = *(const float4*)(bn + 320 + o + 4);
  float4 o0, o1;
  o0.x = (a0 * inv + r0) * sca.x + sha.x;
  o0.y = (a1 * inv + r1) * sca.y + sha.y;
  o0.z = (a2 * inv + r2a) * sca.z + sha.z;
  o0.w = (a3 * inv + r3) * sca.w + sha.w;
  o1.x = (a4 * inv + r4) * scb.x + shb.x;
  o1.y = (a5 * inv + r5) * scb.y + shb.y;
  o1.z = (a6 * inv + r6) * scb.z + shb.z;
  o1.w = (a7 * inv + r7) * scb.w + shb.w;
  *(float4*)(outp + (size_t)node * 64 + o) = o0;
  *(float4*)(outp + (size_t)node * 64 + o + 4) = o1;
}

extern "C" void kernel_launch(void* const* d_in, const int* in_sizes, int n_in,
                              void* d_out, int out_size, void* d_ws, size_t ws_size,
                              hipStream_t stream) {
  const float* x   = (const float*)d_in[0];
  const int*   ei  = (const int*)d_in[1];
  const float* w1l = (const float*)d_in[2];
  const float* b1l = (const float*)d_in[3];
  const float* w1r = (const float*)d_in[4];
  const float* g1  = (const float*)d_in[5];
  const float* be1 = (const float*)d_in[6];
  const float* m1  = (const float*)d_in[7];
  const float* v1  = (const float*)d_in[8];
  const float* w2l = (const float*)d_in[9];
  const float* b2l = (const float*)d_in[10];
  const float* w2r = (const float*)d_in[11];
  const float* g2  = (const float*)d_in[12];
  const float* be2 = (const float*)d_in[13];
  const float* m2  = (const float*)d_in[14];
  const float* v2  = (const float*)d_in[15];
  float* outp = (float*)d_out;

  char* ws = (char*)d_ws;
  // layout (bytes), 16B-aligned:
  //           0 : gcur       (2,048)
  //       2,048 : bucketBase (2,048)
  //       4,096 : deg        (400,000)     -> 404,096
  //     404,096 : offset     (400,000)     -> 804,096
  //     804,096 : pairs      (7,206,912)   -> 8,011,008   (391*4608*4)
  //   8,011,008 : csr        (6,400,000)   -> 14,411,008
  //  14,411,008 : w1c bf16   (32,768)      -> 14,443,776
  //  14,443,776 : w2c bf16   (32,768)      -> 14,476,544
  //  14,476,544 : bn  fp32   (2,048)       -> 14,478,592
  //  14,478,592 : xb  bf16   (12,800,000)  -> 27,278,592
  //  27,278,592 : aggB bf16  (12,800,000)  -> 40,078,592
  //  40,078,592 : t   bf16   (12,800,000)  -> 52,878,592
  //  52,878,592 : r2  bf16   (12,800,000)  -> 65,678,592  (~65.7 MB)
  int*            gcur       = (int*)ws;
  int*            bucketBase = (int*)(ws + 2048);
  int*            deg        = (int*)(ws + 4096);
  int*            offset     = (int*)(ws + 404096);
  unsigned*       pairs      = (unsigned*)(ws + 804096);
  int*            csr        = (int*)(ws + 8011008);
  unsigned short* w1c        = (unsigned short*)(ws + 14411008);
  unsigned short* w2c        = (unsigned short*)(ws + 14443776);
  float*          bn         = (float*)(ws + 14476544);
  unsigned short* xb         = (unsigned short*)(ws + 14478592);
  unsigned short* aggB       = (unsigned short*)(ws + 27278592);
  unsigned short* t          = (unsigned short*)(ws + 40078592);
  unsigned short* r2         = (unsigned short*)(ws + 52878592);

  const int* srcp = ei;
  const int* dstp = ei + NE;

  hipMemsetAsync(gcur, 0, NBUK * sizeof(int), stream);
  hipLaunchKernelGGL(k_bin, dim3(NTIL), dim3(256), 0, stream,
                     srcp, dstp, gcur, pairs);
  hipLaunchKernelGGL(k_bscan, dim3(1), dim3(256), 0, stream, gcur, bucketBase);
  hipLaunchKernelGGL(k_build, dim3(NBUK), dim3(512), 0, stream,
                     pairs, gcur, bucketBase, deg, offset, csr);
  hipLaunchKernelGGL(k_wprep, dim3(64), dim3(256), 0, stream,
                     w1l, w1r, w2l, w2r, b1l, g1, be1, m1, v1,
                     b2l, g2, be2, m2, v2, w1c, w2c, bn);
  hipLaunchKernelGGL(k_cvtx, dim3(NN * 64 / 1024), dim3(256), 0, stream, x, xb);
  hipLaunchKernelGGL(k_aggregate, dim3(NN / 32), dim3(256), 0, stream,
                     xb, deg, offset, csr, aggB);
  hipLaunchKernelGGL(k_gemm12, dim3((NN + 127) / 128), dim3(256), 0, stream,
                     aggB, xb, w1c, w2c, bn, t, r2);
  hipLaunchKernelGGL(k_agg2fin, dim3(NN / 32), dim3(256), 0, stream,
                     t, deg, offset, csr, r2, bn, outp);
}

// Round 13
// 140.391 us; speedup vs baseline: 1.3000x; 1.1845x over previous
//
#include <hip/hip_runtime.h>

#define NN 100000
#define NE 1600000
#define EPSV 1e-5f

#define NBUK 196       // buckets of 512 nodes: bucket = dst >> 9
#define TILE 2048      // edges per k_bin tile
#define NTIL 782       // ceil(NE / TILE); last tile has 512 edges
#define CAP  9216      // per-bucket capacity (mean 8163, sigma ~90 -> +11 sigma)

typedef __attribute__((ext_vector_type(8))) short bf16x8;
typedef __attribute__((ext_vector_type(4))) float f32x4;

__device__ inline unsigned short f2bf(float f) {
  unsigned u = __builtin_bit_cast(unsigned, f);
  unsigned r = u + 0x7FFFu + ((u >> 16) & 1u);
  return (unsigned short)(r >> 16);
}
__device__ inline float bf2f(unsigned short s) {
  unsigned u = ((unsigned)s) << 16;
  return __builtin_bit_cast(float, u);
}

// ---------------- phase 1: per-tile LDS bucket-sort, fully coalesced output ----------------
// No global atomics. pairs is TILE-major: pairs[t*TILE + i] holds tile t sorted by bucket.
__global__ __launch_bounds__(256) void k_bin(const int* __restrict__ src,
                                             const int* __restrict__ dst,
                                             unsigned* __restrict__ pairs,
                                             int* __restrict__ tileCnt,
                                             int* __restrict__ tileLo) {
  __shared__ int cnt[NBUK];   // hist -> cursor
  __shared__ int lo[NBUK];
  __shared__ int ts[256];
  __shared__ unsigned stage[TILE];
  const int tid = threadIdx.x;
  const int t = blockIdx.x;
  const int e0 = t * TILE;
  const int m = min(TILE, NE - e0);

  for (int i = tid; i < NBUK; i += 256) cnt[i] = 0;
  __syncthreads();
  for (int i = tid; i < m; i += 256) {
    atomicAdd(&cnt[dst[e0 + i] >> 9], 1);
  }
  __syncthreads();
  int c = (tid < NBUK) ? cnt[tid] : 0;
  ts[tid] = c;
  __syncthreads();
  for (int d = 1; d < 256; d <<= 1) {
    int v = (tid >= d) ? ts[tid - d] : 0;
    __syncthreads();
    ts[tid] += v;
    __syncthreads();
  }
  if (tid < NBUK) {
    int ex = ts[tid] - c;
    lo[tid] = ex;
    cnt[tid] = ex;  // cursor
  }
  __syncthreads();
  for (int i = tid; i < m; i += 256) {
    int d = dst[e0 + i];
    int s = src[e0 + i];
    int pos = atomicAdd(&cnt[d >> 9], 1);
    stage[pos] = ((unsigned)(d & 511) << 17) | (unsigned)s;
  }
  __syncthreads();
  // fully coalesced writes
  for (int i = tid; i < m; i += 256) pairs[(size_t)t * TILE + i] = stage[i];
  if (tid < NBUK) {
    tileCnt[t * NBUK + tid] = cnt[tid] - lo[tid];
    tileLo[t * NBUK + tid] = lo[tid];
  }
}

// ---------------- phase 1.5a: per-bucket prefix over tiles ----------------
// block b: colBase[b][t] = sum_{t'<t} tileCnt[t'][b]; total[b] = full sum.
__global__ __launch_bounds__(256) void k_colscan(const int* __restrict__ tileCnt,
                                                 int* __restrict__ colBase,
                                                 int* __restrict__ total) {
  __shared__ int ts[256];
  const int tid = threadIdx.x;
  const int b = blockIdx.x;
  int v[4];
  int s = 0;
#pragma unroll
  for (int j = 0; j < 4; ++j) {
    int tt = tid * 4 + j;
    v[j] = (tt < NTIL) ? tileCnt[tt * NBUK + b] : 0;
    s += v[j];
  }
  ts[tid] = s;
  __syncthreads();
  for (int d = 1; d < 256; d <<= 1) {
    int x = (tid >= d) ? ts[tid - d] : 0;
    __syncthreads();
    ts[tid] += x;
    __syncthreads();
  }
  int run = ts[tid] - s;
#pragma unroll
  for (int j = 0; j < 4; ++j) {
    int tt = tid * 4 + j;
    if (tt < NTIL) colBase[(size_t)b * NTIL + tt] = run;
    run += v[j];
  }
  if (tid == 255) total[b] = ts[255];
}

// ---------------- phase 1.5b: scan bucket totals ----------------
__global__ __launch_bounds__(256) void k_bscan(const int* __restrict__ total,
                                               int* __restrict__ bucketBase) {
  __shared__ int ts[256];
  const int tid = threadIdx.x;
  int c = (tid < NBUK) ? min(total[tid], CAP) : 0;
  ts[tid] = c;
  __syncthreads();
  for (int d = 1; d < 256; d <<= 1) {
    int v = (tid >= d) ? ts[tid - d] : 0;
    __syncthreads();
    ts[tid] += v;
    __syncthreads();
  }
  if (tid < NBUK) bucketBase[tid] = ts[tid] - c;
}

// ---------------- phase 2: per-bucket CSR build via GATHER (no scattered writes) ----------------
__global__ __launch_bounds__(512) void k_build(const unsigned* __restrict__ pairs,
                                               const int* __restrict__ tileLo,
                                               const int* __restrict__ colBase,
                                               const int* __restrict__ total,
                                               const int* __restrict__ bucketBase,
                                               int* __restrict__ deg,
                                               int* __restrict__ offset,
                                               int* __restrict__ csr) {
  __shared__ unsigned stageA[CAP];  // bucket-major gathered entries
  __shared__ unsigned stageB[CAP];  // node-sorted entries
  __shared__ int colB[NTIL];
  __shared__ int tLo[NTIL];
  __shared__ int hist[512];
  __shared__ int ts[512];
  const int tid = threadIdx.x;
  const int b = blockIdx.x;
  const int count = min(total[b], CAP);
  const int nbase = b * 512;
  const int nloc = min(512, NN - nbase);
  const int obase = bucketBase[b];

  for (int i = tid; i < NTIL; i += 512) {
    colB[i] = colBase[(size_t)b * NTIL + i];
    tLo[i] = tileLo[i * NBUK + b];
  }
  hist[tid] = 0;
  __syncthreads();
  // gather: output index i comes from tile t = max{t: colB[t] <= i}
  for (int i = tid; i < count; i += 512) {
    int a = 0, z = NTIL - 1;
    while (a < z) {
      int mid = (a + z + 1) >> 1;
      if (colB[mid] <= i) a = mid; else z = mid - 1;
    }
    stageA[i] = pairs[(size_t)a * TILE + tLo[a] + (i - colB[a])];
  }
  __syncthreads();
  for (int i = tid; i < count; i += 512) {
    atomicAdd(&hist[stageA[i] >> 17], 1);
  }
  __syncthreads();
  int s = hist[tid];
  ts[tid] = s;
  __syncthreads();
  for (int d = 1; d < 512; d <<= 1) {
    int v = (tid >= d) ? ts[tid - d] : 0;
    __syncthreads();
    ts[tid] += v;
    __syncthreads();
  }
  int ex = ts[tid] - s;
  if (tid < nloc) {
    deg[nbase + tid] = s;
    offset[nbase + tid] = obase + ex;
  }
  hist[tid] = ex;  // cursor
  __syncthreads();
  for (int i = tid; i < count; i += 512) {
    unsigned e = stageA[i];
    int pos = atomicAdd(&hist[e >> 17], 1);
    stageB[pos] = e & 0x1FFFFu;
  }
  __syncthreads();
  for (int i = tid; i < count; i += 512) csr[obase + i] = (int)stageB[i];
}

// ---------------- fused prep: x->bf16 (all blocks) + weights/BN (blocks < 64) ----------------
__global__ __launch_bounds__(256) void k_prep(const float* __restrict__ x,
                                              unsigned short* __restrict__ xb,
                                              const float* __restrict__ w1l,
                                              const float* __restrict__ w1r,
                                              const float* __restrict__ w2l,
                                              const float* __restrict__ w2r,
                                              const float* __restrict__ b1l,
                                              const float* __restrict__ g1,
                                              const float* __restrict__ be1,
                                              const float* __restrict__ m1,
                                              const float* __restrict__ v1,
                                              const float* __restrict__ b2l,
                                              const float* __restrict__ g2,
                                              const float* __restrict__ be2,
                                              const float* __restrict__ m2,
                                              const float* __restrict__ v2,
                                              unsigned short* __restrict__ w1c,
                                              unsigned short* __restrict__ w2c,
                                              float* __restrict__ bn) {
  int gi = blockIdx.x * 256 + threadIdx.x;
  float4 v = *(const float4*)(x + (size_t)gi * 4);
  ushort4 o;
  o.x = f2bf(v.x); o.y = f2bf(v.y); o.z = f2bf(v.z); o.w = f2bf(v.w);
  *(ushort4*)(xb + (size_t)gi * 4) = o;
  if (blockIdx.x < 64) {
    int i = gi;  // 0..16383
    int oo = i >> 7, k = i & 127;
    float vv1 = (k < 64) ? w1l[oo * 64 + k] : w1r[oo * 64 + (k - 64)];
    w1c[i] = f2bf(vv1);
    float vv2 = (oo < 64) ? w2l[oo * 128 + k] : w2r[(oo - 64) * 128 + k];
    w2c[i] = f2bf(vv2);
    if (i < 128) {
      float sc = g1[i] * rsqrtf(v1[i] + EPSV);
      bn[i] = sc;
      bn[128 + i] = (b1l[i] - m1[i]) * sc + be1[i];
    }
    if (i < 64) {
      float sc = g2[i] * rsqrtf(v2[i] + EPSV);
      bn[256 + i] = sc;
      bn[320 + i] = (b2l[i] - m2[i]) * sc + be2[i];
    }
  }
}

// ---------------- mean-aggregate: 8 lanes/node, 16B per lane ----------------
__global__ __launch_bounds__(256) void k_aggregate(const unsigned short* __restrict__ xb,
                                                   const int* __restrict__ deg,
                                                   const int* __restrict__ offset,
                                                   const int* __restrict__ csr,
                                                   unsigned short* __restrict__ aggB) {
  int tid = threadIdx.x;
  int node = blockIdx.x * 32 + (tid >> 3);
  int j = tid & 7;
  int cnt = deg[node];
  const int* arow = csr + offset[node];
  float a0=0.f,a1=0.f,a2=0.f,a3=0.f,a4=0.f,a5=0.f,a6=0.f,a7=0.f;
  int k = 0;
  for (; k + 4 <= cnt; k += 4) {
    int s0 = arow[k], s1 = arow[k+1], s2 = arow[k+2], s3 = arow[k+3];
    uint4 v0 = *(const uint4*)(xb + (size_t)s0 * 64 + j * 8);
    uint4 v1 = *(const uint4*)(xb + (size_t)s1 * 64 + j * 8);
    uint4 v2 = *(const uint4*)(xb + (size_t)s2 * 64 + j * 8);
    uint4 v3 = *(const uint4*)(xb + (size_t)s3 * 64 + j * 8);
    a0 += bf2f(v0.x & 0xffff) + bf2f(v1.x & 0xffff) + bf2f(v2.x & 0xffff) + bf2f(v3.x & 0xffff);
    a1 += bf2f(v0.x >> 16)    + bf2f(v1.x >> 16)    + bf2f(v2.x >> 16)    + bf2f(v3.x >> 16);
    a2 += bf2f(v0.y & 0xffff) + bf2f(v1.y & 0xffff) + bf2f(v2.y & 0xffff) + bf2f(v3.y & 0xffff);
    a3 += bf2f(v0.y >> 16)    + bf2f(v1.y >> 16)    + bf2f(v2.y >> 16)    + bf2f(v3.y >> 16);
    a4 += bf2f(v0.z & 0xffff) + bf2f(v1.z & 0xffff) + bf2f(v2.z & 0xffff) + bf2f(v3.z & 0xffff);
    a5 += bf2f(v0.z >> 16)    + bf2f(v1.z >> 16)    + bf2f(v2.z >> 16)    + bf2f(v3.z >> 16);
    a6 += bf2f(v0.w & 0xffff) + bf2f(v1.w & 0xffff) + bf2f(v2.w & 0xffff) + bf2f(v3.w & 0xffff);
    a7 += bf2f(v0.w >> 16)    + bf2f(v1.w >> 16)    + bf2f(v2.w >> 16)    + bf2f(v3.w >> 16);
  }
  for (; k < cnt; ++k) {
    int s = arow[k];
    uint4 v = *(const uint4*)(xb + (size_t)s * 64 + j * 8);
    a0 += bf2f(v.x & 0xffff); a1 += bf2f(v.x >> 16);
    a2 += bf2f(v.y & 0xffff); a3 += bf2f(v.y >> 16);
    a4 += bf2f(v.z & 0xffff); a5 += bf2f(v.z >> 16);
    a6 += bf2f(v.w & 0xffff); a7 += bf2f(v.w >> 16);
  }
  float inv = 1.0f / fmaxf((float)cnt, 1.0f);
  ushort4 r0, r1;
  r0.x = f2bf(a0 * inv); r0.y = f2bf(a1 * inv); r0.z = f2bf(a2 * inv); r0.w = f2bf(a3 * inv);
  r1.x = f2bf(a4 * inv); r1.y = f2bf(a5 * inv); r1.z = f2bf(a6 * inv); r1.w = f2bf(a7 * inv);
  *(ushort4*)(aggB + (size_t)node * 64 + j * 8) = r0;
  *(ushort4*)(aggB + (size_t)node * 64 + j * 8 + 4) = r1;
}

// ---------------- fused MFMA: all in-loop operands from LDS ----------------
__global__ __launch_bounds__(256) void k_gemm12(const unsigned short* __restrict__ aggB,
                                                const unsigned short* __restrict__ xb,
                                                const unsigned short* __restrict__ w1c,
                                                const unsigned short* __restrict__ w2c,
                                                const float* __restrict__ bn,
                                                unsigned short* __restrict__ t,
                                                unsigned short* __restrict__ r2) {
  __shared__ unsigned short wlds[32 * 512];       // 32KB
  __shared__ unsigned short hlds[4][2][16 * 128]; // 32KB
  __shared__ float bnlds[384];
  const int tid = threadIdx.x;
  const int w = tid >> 6;
  const int lane = tid & 63;
  const int lr = lane & 15;
  const int q = lane >> 4;
  const int base = blockIdx.x * 128 + w * 32;
  const int nA = base + lr, nB = base + 16 + lr;
  const int cA = min(nA, NN - 1), cB = min(nB, NN - 1);
  const int swz = (lr & 7) << 4;

  bf16x8 fA[4], fB[4];
  {
    const unsigned short* a = aggB + (size_t)cA * 64 + q * 8;
    const unsigned short* xx = xb + (size_t)cA * 64 + q * 8;
    fA[0] = *(const bf16x8*)a;        fA[1] = *(const bf16x8*)(a + 32);
    fA[2] = *(const bf16x8*)xx;       fA[3] = *(const bf16x8*)(xx + 32);
  }
  {
    const unsigned short* a = aggB + (size_t)cB * 64 + q * 8;
    const unsigned short* xx = xb + (size_t)cB * 64 + q * 8;
    fB[0] = *(const bf16x8*)a;        fB[1] = *(const bf16x8*)(a + 32);
    fB[2] = *(const bf16x8*)xx;       fB[3] = *(const bf16x8*)(xx + 32);
  }

  for (int i = tid; i < 384; i += 256) bnlds[i] = bn[i];
  for (int idx = tid; idx < 2048; idx += 256) {
    int f = idx >> 6, l = idx & 63;
    int gofs = ((f >> 2) * 16 + (l & 15)) * 128 + (f & 3) * 32 + (l >> 4) * 8;
    *(uint4*)&wlds[idx * 8] = *(const uint4*)&w1c[gofs];
  }
  __syncthreads();

  char* ldsA = (char*)&hlds[w][0][0];
  char* ldsB = (char*)&hlds[w][1][0];

#pragma unroll
  for (int ot = 0; ot < 8; ++ot) {
    const unsigned short* wp = &wlds[(ot * 4) * 512 + lane * 8];
    bf16x8 w0 = *(const bf16x8*)(wp);
    bf16x8 w1 = *(const bf16x8*)(wp + 512);
    bf16x8 w2 = *(const bf16x8*)(wp + 1024);
    bf16x8 w3 = *(const bf16x8*)(wp + 1536);
    f32x4 aA = {0.f, 0.f, 0.f, 0.f}, aB = {0.f, 0.f, 0.f, 0.f};
    aA = __builtin_amdgcn_mfma_f32_16x16x32_bf16(w0, fA[0], aA, 0, 0, 0);
    aA = __builtin_amdgcn_mfma_f32_16x16x32_bf16(w1, fA[1], aA, 0, 0, 0);
    aA = __builtin_amdgcn_mfma_f32_16x16x32_bf16(w2, fA[2], aA, 0, 0, 0);
    aA = __builtin_amdgcn_mfma_f32_16x16x32_bf16(w3, fA[3], aA, 0, 0, 0);
    aB = __builtin_amdgcn_mfma_f32_16x16x32_bf16(w0, fB[0], aB, 0, 0, 0);
    aB = __builtin_amdgcn_mfma_f32_16x16x32_bf16(w1, fB[1], aB, 0, 0, 0);
    aB = __builtin_amdgcn_mfma_f32_16x16x32_bf16(w2, fB[2], aB, 0, 0, 0);
    aB = __builtin_amdgcn_mfma_f32_16x16x32_bf16(w3, fB[3], aB, 0, 0, 0);
    const int o = ot * 16 + q * 4;
    float4 sc = *(const float4*)&bnlds[o];
    float4 sh = *(const float4*)&bnlds[128 + o];
    ushort4 hA, hB;
    hA.x = f2bf(fmaxf(aA[0] * sc.x + sh.x, 0.f));
    hA.y = f2bf(fmaxf(aA[1] * sc.y + sh.y, 0.f));
    hA.z = f2bf(fmaxf(aA[2] * sc.z + sh.z, 0.f));
    hA.w = f2bf(fmaxf(aA[3] * sc.w + sh.w, 0.f));
    hB.x = f2bf(fmaxf(aB[0] * sc.x + sh.x, 0.f));
    hB.y = f2bf(fmaxf(aB[1] * sc.y + sh.y, 0.f));
    hB.z = f2bf(fmaxf(aB[2] * sc.z + sh.z, 0.f));
    hB.w = f2bf(fmaxf(aB[3] * sc.w + sh.w, 0.f));
    const int wb = lr * 256 + ot * 32 + q * 8;
    *(ushort4*)(ldsA + (wb ^ swz)) = hA;
    *(ushort4*)(ldsB + (wb ^ swz)) = hB;
  }
  __syncthreads();

  for (int idx = tid; idx < 2048; idx += 256) {
    int f = idx >> 6, l = idx & 63;
    int gofs = ((f >> 2) * 16 + (l & 15)) * 128 + (f & 3) * 32 + (l >> 4) * 8;
    *(uint4*)&wlds[idx * 8] = *(const uint4*)&w2c[gofs];
  }
  __syncthreads();

  bf16x8 hA[4], hB[4];
#pragma unroll
  for (int jj = 0; jj < 4; ++jj) {
    const int rb = lr * 256 + jj * 64 + q * 16;
    hA[jj] = *(const bf16x8*)(ldsA + (rb ^ swz));
    hB[jj] = *(const bf16x8*)(ldsB + (rb ^ swz));
  }

#pragma unroll
  for (int ot = 0; ot < 8; ++ot) {
    const unsigned short* wp = &wlds[(ot * 4) * 512 + lane * 8];
    bf16x8 w0 = *(const bf16x8*)(wp);
    bf16x8 w1 = *(const bf16x8*)(wp + 512);
    bf16x8 w2 = *(const bf16x8*)(wp + 1024);
    bf16x8 w3 = *(const bf16x8*)(wp + 1536);
    f32x4 aA = {0.f, 0.f, 0.f, 0.f}, aB = {0.f, 0.f, 0.f, 0.f};
    aA = __builtin_amdgcn_mfma_f32_16x16x32_bf16(w0, hA[0], aA, 0, 0, 0);
    aA = __builtin_amdgcn_mfma_f32_16x16x32_bf16(w1, hA[1], aA, 0, 0, 0);
    aA = __builtin_amdgcn_mfma_f32_16x16x32_bf16(w2, hA[2], aA, 0, 0, 0);
    aA = __builtin_amdgcn_mfma_f32_16x16x32_bf16(w3, hA[3], aA, 0, 0, 0);
    aB = __builtin_amdgcn_mfma_f32_16x16x32_bf16(w0, hB[0], aB, 0, 0, 0);
    aB = __builtin_amdgcn_mfma_f32_16x16x32_bf16(w1, hB[1], aB, 0, 0, 0);
    aB = __builtin_amdgcn_mfma_f32_16x16x32_bf16(w2, hB[2], aB, 0, 0, 0);
    aB = __builtin_amdgcn_mfma_f32_16x16x32_bf16(w3, hB[3], aB, 0, 0, 0);
    ushort4 tv;
    if (ot < 4) {
      const int o = ot * 16 + q * 4;
      tv.x = f2bf(aA[0]); tv.y = f2bf(aA[1]); tv.z = f2bf(aA[2]); tv.w = f2bf(aA[3]);
      if (nA < NN) *(ushort4*)(t + (size_t)nA * 64 + o) = tv;
      tv.x = f2bf(aB[0]); tv.y = f2bf(aB[1]); tv.z = f2bf(aB[2]); tv.w = f2bf(aB[3]);
      if (nB < NN) *(ushort4*)(t + (size_t)nB * 64 + o) = tv;
    } else {
      const int o = (ot - 4) * 16 + q * 4;
      tv.x = f2bf(aA[0]); tv.y = f2bf(aA[1]); tv.z = f2bf(aA[2]); tv.w = f2bf(aA[3]);
      if (nA < NN) *(ushort4*)(r2 + (size_t)nA * 64 + o) = tv;
      tv.x = f2bf(aB[0]); tv.y = f2bf(aB[1]); tv.z = f2bf(aB[2]); tv.w = f2bf(aB[3]);
      if (nB < NN) *(ushort4*)(r2 + (size_t)nB * 64 + o) = tv;
    }
  }
}

// ---------------- layer2 aggregate (bf16 t) + bf16 r2 + BN2: 8 lanes/node ----------------
__global__ __launch_bounds__(256) void k_agg2fin(const unsigned short* __restrict__ t,
                                                 const int* __restrict__ deg,
                                                 const int* __restrict__ offset,
                                                 const int* __restrict__ csr,
                                                 const unsigned short* __restrict__ r2,
                                                 const float* __restrict__ bn,
                                                 float* __restrict__ outp) {
  int tid = threadIdx.x;
  int node = blockIdx.x * 32 + (tid >> 3);
  int j = tid & 7;
  int cnt = deg[node];
  const int* arow = csr + offset[node];
  float a0=0.f,a1=0.f,a2=0.f,a3=0.f,a4=0.f,a5=0.f,a6=0.f,a7=0.f;
  int k = 0;
  for (; k + 4 <= cnt; k += 4) {
    int s0 = arow[k], s1 = arow[k+1], s2 = arow[k+2], s3 = arow[k+3];
    uint4 v0 = *(const uint4*)(t + (size_t)s0 * 64 + j * 8);
    uint4 v1 = *(const uint4*)(t + (size_t)s1 * 64 + j * 8);
    uint4 v2 = *(const uint4*)(t + (size_t)s2 * 64 + j * 8);
    uint4 v3 = *(const uint4*)(t + (size_t)s3 * 64 + j * 8);
    a0 += bf2f(v0.x & 0xffff) + bf2f(v1.x & 0xffff) + bf2f(v2.x & 0xffff) + bf2f(v3.x & 0xffff);
    a1 += bf2f(v0.x >> 16)    + bf2f(v1.x >> 16)    + bf2f(v2.x >> 16)    + bf2f(v3.x >> 16);
    a2 += bf2f(v0.y & 0xffff) + bf2f(v1.y & 0xffff) + bf2f(v2.y & 0xffff) + bf2f(v3.y & 0xffff);
    a3 += bf2f(v0.y >> 16)    + bf2f(v1.y >> 16)    + bf2f(v2.y >> 16)    + bf2f(v3.y >> 16);
    a4 += bf2f(v0.z & 0xffff) + bf2f(v1.z & 0xffff) + bf2f(v2.z & 0xffff) + bf2f(v3.z & 0xffff);
    a5 += bf2f(v0.z >> 16)    + bf2f(v1.z >> 16)    + bf2f(v2.z >> 16)    + bf2f(v3.z >> 16);
    a6 += bf2f(v0.w & 0xffff) + bf2f(v1.w & 0xffff) + bf2f(v2.w & 0xffff) + bf2f(v3.w & 0xffff);
    a7 += bf2f(v0.w >> 16)    + bf2f(v1.w >> 16)    + bf2f(v2.w >> 16)    + bf2f(v3.w >> 16);
  }
  for (; k < cnt; ++k) {
    int s = arow[k];
    uint4 v = *(const uint4*)(t + (size_t)s * 64 + j * 8);
    a0 += bf2f(v.x & 0xffff); a1 += bf2f(v.x >> 16);
    a2 += bf2f(v.y & 0xffff); a3 += bf2f(v.y >> 16);
    a4 += bf2f(v.z & 0xffff); a5 += bf2f(v.z >> 16);
    a6 += bf2f(v.w & 0xffff); a7 += bf2f(v.w >> 16);
  }
  float inv = 1.0f / fmaxf((float)cnt, 1.0f);
  int o = j * 8;
  uint4 rv = *(const uint4*)(r2 + (size_t)node * 64 + o);
  float r0 = bf2f(rv.x & 0xffff), r1 = bf2f(rv.x >> 16);
  float r2a = bf2f(rv.y & 0xffff), r3 = bf2f(rv.y >> 16);
  float r4 = bf2f(rv.z & 0xffff), r5 = bf2f(rv.z >> 16);
  float r6 = bf2f(rv.w & 0xffff), r7 = bf2f(rv.w >> 16);
  float4 sca = *(const float4*)(bn + 256 + o);
  float4 scb = *(const float4*)(bn + 256 + o + 4);
  float4 sha = *(const float4*)(bn + 320 + o);
  float4 shb = *(const float4*)(bn + 320 + o + 4);
  float4 o0, o1;
  o0.x = (a0 * inv + r0) * sca.x + sha.x;
  o0.y = (a1 * inv + r1) * sca.y + sha.y;
  o0.z = (a2 * inv + r2a) * sca.z + sha.z;
  o0.w = (a3 * inv + r3) * sca.w + sha.w;
  o1.x = (a4 * inv + r4) * scb.x + shb.x;
  o1.y = (a5 * inv + r5) * scb.y + shb.y;
  o1.z = (a6 * inv + r6) * scb.z + shb.z;
  o1.w = (a7 * inv + r7) * scb.w + shb.w;
  *(float4*)(outp + (size_t)node * 64 + o) = o0;
  *(float4*)(outp + (size_t)node * 64 + o + 4) = o1;
}

extern "C" void kernel_launch(void* const* d_in, const int* in_sizes, int n_in,
                              void* d_out, int out_size, void* d_ws, size_t ws_size,
                              hipStream_t stream) {
  const float* x   = (const float*)d_in[0];
  const int*   ei  = (const int*)d_in[1];
  const float* w1l = (const float*)d_in[2];
  const float* b1l = (const float*)d_in[3];
  const float* w1r = (const float*)d_in[4];
  const float* g1  = (const float*)d_in[5];
  const float* be1 = (const float*)d_in[6];
  const float* m1  = (const float*)d_in[7];
  const float* v1  = (const float*)d_in[8];
  const float* w2l = (const float*)d_in[9];
  const float* b2l = (const float*)d_in[10];
  const float* w2r = (const float*)d_in[11];
  const float* g2  = (const float*)d_in[12];
  const float* be2 = (const float*)d_in[13];
  const float* m2  = (const float*)d_in[14];
  const float* v2  = (const float*)d_in[15];
  float* outp = (float*)d_out;

  char* ws = (char*)d_ws;
  // layout (bytes), 16B-aligned:
  //           0 : tileCnt    (613,120)     [782][196]
  //     613,120 : tileLo     (613,120)     [782][196]
  //   1,226,240 : colBase    (613,120)     [196][782]
  //   1,839,360 : total      (1,024)
  //   1,840,384 : bucketBase (1,024)
  //   1,841,408 : deg        (400,000)     -> 2,241,408
  //   2,241,408 : offset     (400,000)     -> 2,641,408
  //   2,641,408 : pairs      (6,406,144)   -> 9,047,552   (tile-major)
  //   9,047,552 : csr        (6,400,000)   -> 15,447,552
  //  15,447,552 : w1c bf16   (32,768)      -> 15,480,320
  //  15,480,320 : w2c bf16   (32,768)      -> 15,513,088
  //  15,513,088 : bn  fp32   (2,048)       -> 15,515,136
  //  15,515,136 : xb  bf16   (12,800,000)  -> 28,315,136
  //  28,315,136 : aggB bf16  (12,800,000)  -> 41,115,136
  //  41,115,136 : t   bf16   (12,800,000)  -> 53,915,136
  //  53,915,136 : r2  bf16   (12,800,000)  -> 66,715,136  (~67 MB)
  int*            tileCnt    = (int*)ws;
  int*            tileLo     = (int*)(ws + 613120);
  int*            colBase    = (int*)(ws + 1226240);
  int*            total      = (int*)(ws + 1839360);
  int*            bucketBase = (int*)(ws + 1840384);
  int*            deg        = (int*)(ws + 1841408);
  int*            offset     = (int*)(ws + 2241408);
  unsigned*       pairs      = (unsigned*)(ws + 2641408);
  int*            csr        = (int*)(ws + 9047552);
  unsigned short* w1c        = (unsigned short*)(ws + 15447552);
  unsigned short* w2c        = (unsigned short*)(ws + 15480320);
  float*          bn         = (float*)(ws + 15513088);
  unsigned short* xb         = (unsigned short*)(ws + 15515136);
  unsigned short* aggB       = (unsigned short*)(ws + 28315136);
  unsigned short* t          = (unsigned short*)(ws + 41115136);
  unsigned short* r2         = (unsigned short*)(ws + 53915136);

  const int* srcp = ei;
  const int* dstp = ei + NE;

  hipLaunchKernelGGL(k_prep, dim3(NN * 64 / 1024), dim3(256), 0, stream,
                     x, xb, w1l, w1r, w2l, w2r, b1l, g1, be1, m1, v1,
                     b2l, g2, be2, m2, v2, w1c, w2c, bn);
  hipLaunchKernelGGL(k_bin, dim3(NTIL), dim3(256), 0, stream,
                     srcp, dstp, pairs, tileCnt, tileLo);
  hipLaunchKernelGGL(k_colscan, dim3(NBUK), dim3(256), 0, stream,
                     tileCnt, colBase, total);
  hipLaunchKernelGGL(k_bscan, dim3(1), dim3(256), 0, stream, total, bucketBase);
  hipLaunchKernelGGL(k_build, dim3(NBUK), dim3(512), 0, stream,
                     pairs, tileLo, colBase, total, bucketBase, deg, offset, csr);
  hipLaunchKernelGGL(k_aggregate, dim3(NN / 32), dim3(256), 0, stream,
                     xb, deg, offset, csr, aggB);
  hipLaunchKernelGGL(k_gemm12, dim3((NN + 127) / 128), dim3(256), 0, stream,
                     aggB, xb, w1c, w2c, bn, t, r2);
  hipLaunchKernelGGL(k_agg2fin, dim3(NN / 32), dim3(256), 0, stream,
                     t, deg, offset, csr, r2, bn, outp);
}

// Round 14
// 135.424 us; speedup vs baseline: 1.3476x; 1.0367x over previous
//
#include <hip/hip_runtime.h>

#define NN 100000
#define NE 1600000
#define EPSV 1e-5f

#define NBUK 196       // buckets of 512 nodes: bucket = dst >> 9
#define TILE 2048      // edges per k_bin tile
#define NTIL 782       // ceil(NE / TILE); last tile has 512 edges
#define CAP  9216      // per-bucket capacity (mean 8163, sigma ~90 -> +11 sigma)

typedef __attribute__((ext_vector_type(8))) short bf16x8;
typedef __attribute__((ext_vector_type(4))) float f32x4;

__device__ inline unsigned short f2bf(float f) {
  unsigned u = __builtin_bit_cast(unsigned, f);
  unsigned r = u + 0x7FFFu + ((u >> 16) & 1u);
  return (unsigned short)(r >> 16);
}
__device__ inline float bf2f(unsigned short s) {
  unsigned u = ((unsigned)s) << 16;
  return __builtin_bit_cast(float, u);
}

// async global->LDS, 16B per lane; LDS dest = wave-uniform base + lane*16
__device__ __forceinline__ void gload_lds16(const unsigned short* g, unsigned short* l) {
  __builtin_amdgcn_global_load_lds(
      (const __attribute__((address_space(1))) void*)g,
      (__attribute__((address_space(3))) void*)l, 16, 0, 0);
}

// ---------------- phase 1: per-tile LDS bucket-sort, fully coalesced output ----------------
__global__ __launch_bounds__(256) void k_bin(const int* __restrict__ src,
                                             const int* __restrict__ dst,
                                             unsigned* __restrict__ pairs,
                                             int* __restrict__ tileCnt,
                                             int* __restrict__ tileLo) {
  __shared__ int cnt[NBUK];
  __shared__ int lo[NBUK];
  __shared__ int ts[256];
  __shared__ unsigned stage[TILE];
  const int tid = threadIdx.x;
  const int t = blockIdx.x;
  const int e0 = t * TILE;
  const int m = min(TILE, NE - e0);

  for (int i = tid; i < NBUK; i += 256) cnt[i] = 0;
  __syncthreads();
  for (int i = tid; i < m; i += 256) {
    atomicAdd(&cnt[dst[e0 + i] >> 9], 1);
  }
  __syncthreads();
  int c = (tid < NBUK) ? cnt[tid] : 0;
  ts[tid] = c;
  __syncthreads();
  for (int d = 1; d < 256; d <<= 1) {
    int v = (tid >= d) ? ts[tid - d] : 0;
    __syncthreads();
    ts[tid] += v;
    __syncthreads();
  }
  if (tid < NBUK) {
    int ex = ts[tid] - c;
    lo[tid] = ex;
    cnt[tid] = ex;
  }
  __syncthreads();
  for (int i = tid; i < m; i += 256) {
    int d = dst[e0 + i];
    int s = src[e0 + i];
    int pos = atomicAdd(&cnt[d >> 9], 1);
    stage[pos] = ((unsigned)(d & 511) << 17) | (unsigned)s;
  }
  __syncthreads();
  for (int i = tid; i < m; i += 256) pairs[(size_t)t * TILE + i] = stage[i];
  if (tid < NBUK) {
    tileCnt[t * NBUK + tid] = cnt[tid] - lo[tid];
    tileLo[t * NBUK + tid] = lo[tid];
  }
}

// ---------------- phase 1.5a: per-bucket prefix over tiles ----------------
__global__ __launch_bounds__(256) void k_colscan(const int* __restrict__ tileCnt,
                                                 int* __restrict__ colBase,
                                                 int* __restrict__ total) {
  __shared__ int ts[256];
  const int tid = threadIdx.x;
  const int b = blockIdx.x;
  int v[4];
  int s = 0;
#pragma unroll
  for (int j = 0; j < 4; ++j) {
    int tt = tid * 4 + j;
    v[j] = (tt < NTIL) ? tileCnt[tt * NBUK + b] : 0;
    s += v[j];
  }
  ts[tid] = s;
  __syncthreads();
  for (int d = 1; d < 256; d <<= 1) {
    int x = (tid >= d) ? ts[tid - d] : 0;
    __syncthreads();
    ts[tid] += x;
    __syncthreads();
  }
  int run = ts[tid] - s;
#pragma unroll
  for (int j = 0; j < 4; ++j) {
    int tt = tid * 4 + j;
    if (tt < NTIL) colBase[(size_t)b * NTIL + tt] = run;
    run += v[j];
  }
  if (tid == 255) total[b] = ts[255];
}

// ---------------- phase 1.5b: scan bucket totals ----------------
__global__ __launch_bounds__(256) void k_bscan(const int* __restrict__ total,
                                               int* __restrict__ bucketBase) {
  __shared__ int ts[256];
  const int tid = threadIdx.x;
  int c = (tid < NBUK) ? min(total[tid], CAP) : 0;
  ts[tid] = c;
  __syncthreads();
  for (int d = 1; d < 256; d <<= 1) {
    int v = (tid >= d) ? ts[tid - d] : 0;
    __syncthreads();
    ts[tid] += v;
    __syncthreads();
  }
  if (tid < NBUK) bucketBase[tid] = ts[tid] - c;
}

// ---------------- phase 2: per-bucket CSR build via GATHER ----------------
__global__ __launch_bounds__(512) void k_build(const unsigned* __restrict__ pairs,
                                               const int* __restrict__ tileLo,
                                               const int* __restrict__ colBase,
                                               const int* __restrict__ total,
                                               const int* __restrict__ bucketBase,
                                               int* __restrict__ deg,
                                               int* __restrict__ offset,
                                               int* __restrict__ csr) {
  __shared__ unsigned stageA[CAP];
  __shared__ unsigned stageB[CAP];
  __shared__ int colB[NTIL];
  __shared__ int tLo[NTIL];
  __shared__ int hist[512];
  __shared__ int ts[512];
  const int tid = threadIdx.x;
  const int b = blockIdx.x;
  const int count = min(total[b], CAP);
  const int nbase = b * 512;
  const int nloc = min(512, NN - nbase);
  const int obase = bucketBase[b];

  for (int i = tid; i < NTIL; i += 512) {
    colB[i] = colBase[(size_t)b * NTIL + i];
    tLo[i] = tileLo[i * NBUK + b];
  }
  hist[tid] = 0;
  __syncthreads();
  for (int i = tid; i < count; i += 512) {
    int a = 0, z = NTIL - 1;
    while (a < z) {
      int mid = (a + z + 1) >> 1;
      if (colB[mid] <= i) a = mid; else z = mid - 1;
    }
    stageA[i] = pairs[(size_t)a * TILE + tLo[a] + (i - colB[a])];
  }
  __syncthreads();
  for (int i = tid; i < count; i += 512) {
    atomicAdd(&hist[stageA[i] >> 17], 1);
  }
  __syncthreads();
  int s = hist[tid];
  ts[tid] = s;
  __syncthreads();
  for (int d = 1; d < 512; d <<= 1) {
    int v = (tid >= d) ? ts[tid - d] : 0;
    __syncthreads();
    ts[tid] += v;
    __syncthreads();
  }
  int ex = ts[tid] - s;
  if (tid < nloc) {
    deg[nbase + tid] = s;
    offset[nbase + tid] = obase + ex;
  }
  hist[tid] = ex;
  __syncthreads();
  for (int i = tid; i < count; i += 512) {
    unsigned e = stageA[i];
    int pos = atomicAdd(&hist[e >> 17], 1);
    stageB[pos] = e & 0x1FFFFu;
  }
  __syncthreads();
  for (int i = tid; i < count; i += 512) csr[obase + i] = (int)stageB[i];
}

// ---------------- fused prep: x->bf16 + weights/BN ----------------
__global__ __launch_bounds__(256) void k_prep(const float* __restrict__ x,
                                              unsigned short* __restrict__ xb,
                                              const float* __restrict__ w1l,
                                              const float* __restrict__ w1r,
                                              const float* __restrict__ w2l,
                                              const float* __restrict__ w2r,
                                              const float* __restrict__ b1l,
                                              const float* __restrict__ g1,
                                              const float* __restrict__ be1,
                                              const float* __restrict__ m1,
                                              const float* __restrict__ v1,
                                              const float* __restrict__ b2l,
                                              const float* __restrict__ g2,
                                              const float* __restrict__ be2,
                                              const float* __restrict__ m2,
                                              const float* __restrict__ v2,
                                              unsigned short* __restrict__ w1c,
                                              unsigned short* __restrict__ w2c,
                                              float* __restrict__ bn) {
  int gi = blockIdx.x * 256 + threadIdx.x;
  float4 v = *(const float4*)(x + (size_t)gi * 4);
  ushort4 o;
  o.x = f2bf(v.x); o.y = f2bf(v.y); o.z = f2bf(v.z); o.w = f2bf(v.w);
  *(ushort4*)(xb + (size_t)gi * 4) = o;
  if (blockIdx.x < 64) {
    int i = gi;  // 0..16383
    int oo = i >> 7, k = i & 127;
    float vv1 = (k < 64) ? w1l[oo * 64 + k] : w1r[oo * 64 + (k - 64)];
    w1c[i] = f2bf(vv1);
    float vv2 = (oo < 64) ? w2l[oo * 128 + k] : w2r[(oo - 64) * 128 + k];
    w2c[i] = f2bf(vv2);
    if (i < 128) {
      float sc = g1[i] * rsqrtf(v1[i] + EPSV);
      bn[i] = sc;
      bn[128 + i] = (b1l[i] - m1[i]) * sc + be1[i];
    }
    if (i < 64) {
      float sc = g2[i] * rsqrtf(v2[i] + EPSV);
      bn[256 + i] = sc;
      bn[320 + i] = (b2l[i] - m2[i]) * sc + be2[i];
    }
  }
}

// ---------------- mean-aggregate: 8 lanes/node, 16B per lane ----------------
__global__ __launch_bounds__(256) void k_aggregate(const unsigned short* __restrict__ xb,
                                                   const int* __restrict__ deg,
                                                   const int* __restrict__ offset,
                                                   const int* __restrict__ csr,
                                                   unsigned short* __restrict__ aggB) {
  int tid = threadIdx.x;
  int node = blockIdx.x * 32 + (tid >> 3);
  int j = tid & 7;
  int cnt = deg[node];
  const int* arow = csr + offset[node];
  float a0=0.f,a1=0.f,a2=0.f,a3=0.f,a4=0.f,a5=0.f,a6=0.f,a7=0.f;
  int k = 0;
  for (; k + 4 <= cnt; k += 4) {
    int s0 = arow[k], s1 = arow[k+1], s2 = arow[k+2], s3 = arow[k+3];
    uint4 v0 = *(const uint4*)(xb + (size_t)s0 * 64 + j * 8);
    uint4 v1 = *(const uint4*)(xb + (size_t)s1 * 64 + j * 8);
    uint4 v2 = *(const uint4*)(xb + (size_t)s2 * 64 + j * 8);
    uint4 v3 = *(const uint4*)(xb + (size_t)s3 * 64 + j * 8);
    a0 += bf2f(v0.x & 0xffff) + bf2f(v1.x & 0xffff) + bf2f(v2.x & 0xffff) + bf2f(v3.x & 0xffff);
    a1 += bf2f(v0.x >> 16)    + bf2f(v1.x >> 16)    + bf2f(v2.x >> 16)    + bf2f(v3.x >> 16);
    a2 += bf2f(v0.y & 0xffff) + bf2f(v1.y & 0xffff) + bf2f(v2.y & 0xffff) + bf2f(v3.y & 0xffff);
    a3 += bf2f(v0.y >> 16)    + bf2f(v1.y >> 16)    + bf2f(v2.y >> 16)    + bf2f(v3.y >> 16);
    a4 += bf2f(v0.z & 0xffff) + bf2f(v1.z & 0xffff) + bf2f(v2.z & 0xffff) + bf2f(v3.z & 0xffff);
    a5 += bf2f(v0.z >> 16)    + bf2f(v1.z >> 16)    + bf2f(v2.z >> 16)    + bf2f(v3.z >> 16);
    a6 += bf2f(v0.w & 0xffff) + bf2f(v1.w & 0xffff) + bf2f(v2.w & 0xffff) + bf2f(v3.w & 0xffff);
    a7 += bf2f(v0.w >> 16)    + bf2f(v1.w >> 16)    + bf2f(v2.w >> 16)    + bf2f(v3.w >> 16);
  }
  for (; k < cnt; ++k) {
    int s = arow[k];
    uint4 v = *(const uint4*)(xb + (size_t)s * 64 + j * 8);
    a0 += bf2f(v.x & 0xffff); a1 += bf2f(v.x >> 16);
    a2 += bf2f(v.y & 0xffff); a3 += bf2f(v.y >> 16);
    a4 += bf2f(v.z & 0xffff); a5 += bf2f(v.z >> 16);
    a6 += bf2f(v.w & 0xffff); a7 += bf2f(v.w >> 16);
  }
  float inv = 1.0f / fmaxf((float)cnt, 1.0f);
  ushort4 r0, r1;
  r0.x = f2bf(a0 * inv); r0.y = f2bf(a1 * inv); r0.z = f2bf(a2 * inv); r0.w = f2bf(a3 * inv);
  r1.x = f2bf(a4 * inv); r1.y = f2bf(a5 * inv); r1.z = f2bf(a6 * inv); r1.w = f2bf(a7 * inv);
  *(ushort4*)(aggB + (size_t)node * 64 + j * 8) = r0;
  *(ushort4*)(aggB + (size_t)node * 64 + j * 8 + 4) = r1;
}

// ---------------- fused MFMA: weight-stationary, async staging, 1 barrier ----------------
// 512 threads = 8 waves, 1 tile (32 nodes) per wave. LDS: 32KB w1 + 32KB w2 +
// 64KB h (8KB/wave) + 1.5KB bn = 129.5KB -> 1 block/CU, 8 waves/CU.
// Weights staged ONCE per block via async global_load_lds; no barriers after the first.
__global__ __launch_bounds__(512, 1) void k_gemm12(const unsigned short* __restrict__ aggB,
                                                   const unsigned short* __restrict__ xb,
                                                   const unsigned short* __restrict__ w1c,
                                                   const unsigned short* __restrict__ w2c,
                                                   const float* __restrict__ bn,
                                                   unsigned short* __restrict__ t,
                                                   unsigned short* __restrict__ r2) {
  __shared__ unsigned short w1lds[32 * 512];      // 32KB fragment-major
  __shared__ unsigned short w2lds[32 * 512];      // 32KB fragment-major
  __shared__ unsigned short hlds[8][2][16 * 128]; // 64KB
  __shared__ float bnlds[384];                    // 1.5KB
  const int tid = threadIdx.x;
  const int w = tid >> 6;
  const int lane = tid & 63;
  const int lr = lane & 15;
  const int q = lane >> 4;
  const int tile = blockIdx.x * 8 + w;
  const int base = tile * 32;
  const int nA = base + lr, nB = base + 16 + lr;
  const int cA = min(nA, NN - 1), cB = min(nB, NN - 1);
  const int swz = (lr & 7) << 4;

  // async-stage both weight matrices, fragment-major (frag f at f*512 ushorts)
#pragma unroll
  for (int it = 0; it < 4; ++it) {
    int idx = it * 512 + tid;
    int f = idx >> 6, l = idx & 63;
    int gofs = ((f >> 2) * 16 + (l & 15)) * 128 + (f & 3) * 32 + (l >> 4) * 8;
    gload_lds16(w1c + gofs, &w1lds[(it * 512 + w * 64) * 8]);
    gload_lds16(w2c + gofs, &w2lds[(it * 512 + w * 64) * 8]);
  }
  if (tid < 384) bnlds[tid] = bn[tid];

  // activation loads (independent of staging; latency overlaps)
  bf16x8 fA[4], fB[4];
  {
    const unsigned short* a = aggB + (size_t)cA * 64 + q * 8;
    const unsigned short* xx = xb + (size_t)cA * 64 + q * 8;
    fA[0] = *(const bf16x8*)a;        fA[1] = *(const bf16x8*)(a + 32);
    fA[2] = *(const bf16x8*)xx;       fA[3] = *(const bf16x8*)(xx + 32);
  }
  {
    const unsigned short* a = aggB + (size_t)cB * 64 + q * 8;
    const unsigned short* xx = xb + (size_t)cB * 64 + q * 8;
    fB[0] = *(const bf16x8*)a;        fB[1] = *(const bf16x8*)(a + 32);
    fB[2] = *(const bf16x8*)xx;       fB[3] = *(const bf16x8*)(xx + 32);
  }
  __syncthreads();  // drains global_load_lds (vmcnt) + bn writes
  if (base >= NN) return;

  char* ldsA = (char*)&hlds[w][0][0];
  char* ldsB = (char*)&hlds[w][1][0];

  // ---- layer 1: h = relu(acc*SC1 + SH1) -> swizzled per-wave h-LDS ----
#pragma unroll
  for (int ot = 0; ot < 8; ++ot) {
    const unsigned short* wp = &w1lds[(ot * 4) * 512 + lane * 8];
    bf16x8 w0 = *(const bf16x8*)(wp);
    bf16x8 w1 = *(const bf16x8*)(wp + 512);
    bf16x8 w2 = *(const bf16x8*)(wp + 1024);
    bf16x8 w3 = *(const bf16x8*)(wp + 1536);
    f32x4 aA = {0.f, 0.f, 0.f, 0.f}, aB = {0.f, 0.f, 0.f, 0.f};
    aA = __builtin_amdgcn_mfma_f32_16x16x32_bf16(w0, fA[0], aA, 0, 0, 0);
    aA = __builtin_amdgcn_mfma_f32_16x16x32_bf16(w1, fA[1], aA, 0, 0, 0);
    aA = __builtin_amdgcn_mfma_f32_16x16x32_bf16(w2, fA[2], aA, 0, 0, 0);
    aA = __builtin_amdgcn_mfma_f32_16x16x32_bf16(w3, fA[3], aA, 0, 0, 0);
    aB = __builtin_amdgcn_mfma_f32_16x16x32_bf16(w0, fB[0], aB, 0, 0, 0);
    aB = __builtin_amdgcn_mfma_f32_16x16x32_bf16(w1, fB[1], aB, 0, 0, 0);
    aB = __builtin_amdgcn_mfma_f32_16x16x32_bf16(w2, fB[2], aB, 0, 0, 0);
    aB = __builtin_amdgcn_mfma_f32_16x16x32_bf16(w3, fB[3], aB, 0, 0, 0);
    const int o = ot * 16 + q * 4;
    float4 sc = *(const float4*)&bnlds[o];
    float4 sh = *(const float4*)&bnlds[128 + o];
    ushort4 hA, hB;
    hA.x = f2bf(fmaxf(aA[0] * sc.x + sh.x, 0.f));
    hA.y = f2bf(fmaxf(aA[1] * sc.y + sh.y, 0.f));
    hA.z = f2bf(fmaxf(aA[2] * sc.z + sh.z, 0.f));
    hA.w = f2bf(fmaxf(aA[3] * sc.w + sh.w, 0.f));
    hB.x = f2bf(fmaxf(aB[0] * sc.x + sh.x, 0.f));
    hB.y = f2bf(fmaxf(aB[1] * sc.y + sh.y, 0.f));
    hB.z = f2bf(fmaxf(aB[2] * sc.z + sh.z, 0.f));
    hB.w = f2bf(fmaxf(aB[3] * sc.w + sh.w, 0.f));
    const int wb = lr * 256 + ot * 32 + q * 8;
    *(ushort4*)(ldsA + (wb ^ swz)) = hA;
    *(ushort4*)(ldsB + (wb ^ swz)) = hB;
  }

  // read back h as B-fragments (same-wave ds; compiler inserts lgkmcnt)
  bf16x8 hA[4], hB[4];
#pragma unroll
  for (int jj = 0; jj < 4; ++jj) {
    const int rb = lr * 256 + jj * 64 + q * 16;
    hA[jj] = *(const bf16x8*)(ldsA + (rb ^ swz));
    hB[jj] = *(const bf16x8*)(ldsB + (rb ^ swz));
  }

  // ---- layer 2: ot<4 -> t (bf16), ot>=4 -> r2 (bf16, bias folded into BN2) ----
#pragma unroll
  for (int ot = 0; ot < 8; ++ot) {
    const unsigned short* wp = &w2lds[(ot * 4) * 512 + lane * 8];
    bf16x8 w0 = *(const bf16x8*)(wp);
    bf16x8 w1 = *(const bf16x8*)(wp + 512);
    bf16x8 w2 = *(const bf16x8*)(wp + 1024);
    bf16x8 w3 = *(const bf16x8*)(wp + 1536);
    f32x4 aA = {0.f, 0.f, 0.f, 0.f}, aB = {0.f, 0.f, 0.f, 0.f};
    aA = __builtin_amdgcn_mfma_f32_16x16x32_bf16(w0, hA[0], aA, 0, 0, 0);
    aA = __builtin_amdgcn_mfma_f32_16x16x32_bf16(w1, hA[1], aA, 0, 0, 0);
    aA = __builtin_amdgcn_mfma_f32_16x16x32_bf16(w2, hA[2], aA, 0, 0, 0);
    aA = __builtin_amdgcn_mfma_f32_16x16x32_bf16(w3, hA[3], aA, 0, 0, 0);
    aB = __builtin_amdgcn_mfma_f32_16x16x32_bf16(w0, hB[0], aB, 0, 0, 0);
    aB = __builtin_amdgcn_mfma_f32_16x16x32_bf16(w1, hB[1], aB, 0, 0, 0);
    aB = __builtin_amdgcn_mfma_f32_16x16x32_bf16(w2, hB[2], aB, 0, 0, 0);
    aB = __builtin_amdgcn_mfma_f32_16x16x32_bf16(w3, hB[3], aB, 0, 0, 0);
    ushort4 tv;
    if (ot < 4) {
      const int o = ot * 16 + q * 4;
      tv.x = f2bf(aA[0]); tv.y = f2bf(aA[1]); tv.z = f2bf(aA[2]); tv.w = f2bf(aA[3]);
      if (nA < NN) *(ushort4*)(t + (size_t)nA * 64 + o) = tv;
      tv.x = f2bf(aB[0]); tv.y = f2bf(aB[1]); tv.z = f2bf(aB[2]); tv.w = f2bf(aB[3]);
      if (nB < NN) *(ushort4*)(t + (size_t)nB * 64 + o) = tv;
    } else {
      const int o = (ot - 4) * 16 + q * 4;
      tv.x = f2bf(aA[0]); tv.y = f2bf(aA[1]); tv.z = f2bf(aA[2]); tv.w = f2bf(aA[3]);
      if (nA < NN) *(ushort4*)(r2 + (size_t)nA * 64 + o) = tv;
      tv.x = f2bf(aB[0]); tv.y = f2bf(aB[1]); tv.z = f2bf(aB[2]); tv.w = f2bf(aB[3]);
      if (nB < NN) *(ushort4*)(r2 + (size_t)nB * 64 + o) = tv;
    }
  }
}

// ---------------- layer2 aggregate (bf16 t) + bf16 r2 + BN2: 8 lanes/node ----------------
__global__ __launch_bounds__(256) void k_agg2fin(const unsigned short* __restrict__ t,
                                                 const int* __restrict__ deg,
                                                 const int* __restrict__ offset,
                                                 const int* __restrict__ csr,
                                                 const unsigned short* __restrict__ r2,
                                                 const float* __restrict__ bn,
                                                 float* __restrict__ outp) {
  int tid = threadIdx.x;
  int node = blockIdx.x * 32 + (tid >> 3);
  int j = tid & 7;
  int cnt = deg[node];
  const int* arow = csr + offset[node];
  float a0=0.f,a1=0.f,a2=0.f,a3=0.f,a4=0.f,a5=0.f,a6=0.f,a7=0.f;
  int k = 0;
  for (; k + 4 <= cnt; k += 4) {
    int s0 = arow[k], s1 = arow[k+1], s2 = arow[k+2], s3 = arow[k+3];
    uint4 v0 = *(const uint4*)(t + (size_t)s0 * 64 + j * 8);
    uint4 v1 = *(const uint4*)(t + (size_t)s1 * 64 + j * 8);
    uint4 v2 = *(const uint4*)(t + (size_t)s2 * 64 + j * 8);
    uint4 v3 = *(const uint4*)(t + (size_t)s3 * 64 + j * 8);
    a0 += bf2f(v0.x & 0xffff) + bf2f(v1.x & 0xffff) + bf2f(v2.x & 0xffff) + bf2f(v3.x & 0xffff);
    a1 += bf2f(v0.x >> 16)    + bf2f(v1.x >> 16)    + bf2f(v2.x >> 16)    + bf2f(v3.x >> 16);
    a2 += bf2f(v0.y & 0xffff) + bf2f(v1.y & 0xffff) + bf2f(v2.y & 0xffff) + bf2f(v3.y & 0xffff);
    a3 += bf2f(v0.y >> 16)    + bf2f(v1.y >> 16)    + bf2f(v2.y >> 16)    + bf2f(v3.y >> 16);
    a4 += bf2f(v0.z & 0xffff) + bf2f(v1.z & 0xffff) + bf2f(v2.z & 0xffff) + bf2f(v3.z & 0xffff);
    a5 += bf2f(v0.z >> 16)    + bf2f(v1.z >> 16)    + bf2f(v2.z >> 16)    + bf2f(v3.z >> 16);
    a6 += bf2f(v0.w & 0xffff) + bf2f(v1.w & 0xffff) + bf2f(v2.w & 0xffff) + bf2f(v3.w & 0xffff);
    a7 += bf2f(v0.w >> 16)    + bf2f(v1.w >> 16)    + bf2f(v2.w >> 16)    + bf2f(v3.w >> 16);
  }
  for (; k < cnt; ++k) {
    int s = arow[k];
    uint4 v = *(const uint4*)(t + (size_t)s * 64 + j * 8);
    a0 += bf2f(v.x & 0xffff); a1 += bf2f(v.x >> 16);
    a2 += bf2f(v.y & 0xffff); a3 += bf2f(v.y >> 16);
    a4 += bf2f(v.z & 0xffff); a5 += bf2f(v.z >> 16);
    a6 += bf2f(v.w & 0xffff); a7 += bf2f(v.w >> 16);
  }
  float inv = 1.0f / fmaxf((float)cnt, 1.0f);
  int o = j * 8;
  uint4 rv = *(const uint4*)(r2 + (size_t)node * 64 + o);
  float r0 = bf2f(rv.x & 0xffff), r1 = bf2f(rv.x >> 16);
  float r2a = bf2f(rv.y & 0xffff), r3 = bf2f(rv.y >> 16);
  float r4 = bf2f(rv.z & 0xffff), r5 = bf2f(rv.z >> 16);
  float r6 = bf2f(rv.w & 0xffff), r7 = bf2f(rv.w >> 16);
  float4 sca = *(const float4*)(bn + 256 + o);
  float4 scb = *(const float4*)(bn + 256 + o + 4);
  float4 sha = *(const float4*)(bn + 320 + o);
  float4 shb = *(const float4*)(bn + 320 + o + 4);
  float4 o0, o1;
  o0.x = (a0 * inv + r0) * sca.x + sha.x;
  o0.y = (a1 * inv + r1) * sca.y + sha.y;
  o0.z = (a2 * inv + r2a) * sca.z + sha.z;
  o0.w = (a3 * inv + r3) * sca.w + sha.w;
  o1.x = (a4 * inv + r4) * scb.x + shb.x;
  o1.y = (a5 * inv + r5) * scb.y + shb.y;
  o1.z = (a6 * inv + r6) * scb.z + shb.z;
  o1.w = (a7 * inv + r7) * scb.w + shb.w;
  *(float4*)(outp + (size_t)node * 64 + o) = o0;
  *(float4*)(outp + (size_t)node * 64 + o + 4) = o1;
}

extern "C" void kernel_launch(void* const* d_in, const int* in_sizes, int n_in,
                              void* d_out, int out_size, void* d_ws, size_t ws_size,
                              hipStream_t stream) {
  const float* x   = (const float*)d_in[0];
  const int*   ei  = (const int*)d_in[1];
  const float* w1l = (const float*)d_in[2];
  const float* b1l = (const float*)d_in[3];
  const float* w1r = (const float*)d_in[4];
  const float* g1  = (const float*)d_in[5];
  const float* be1 = (const float*)d_in[6];
  const float* m1  = (const float*)d_in[7];
  const float* v1  = (const float*)d_in[8];
  const float* w2l = (const float*)d_in[9];
  const float* b2l = (const float*)d_in[10];
  const float* w2r = (const float*)d_in[11];
  const float* g2  = (const float*)d_in[12];
  const float* be2 = (const float*)d_in[13];
  const float* m2  = (const float*)d_in[14];
  const float* v2  = (const float*)d_in[15];
  float* outp = (float*)d_out;

  char* ws = (char*)d_ws;
  // layout (bytes), 16B-aligned:
  //           0 : tileCnt    (613,120)     [782][196]
  //     613,120 : tileLo     (613,120)     [782][196]
  //   1,226,240 : colBase    (613,120)     [196][782]
  //   1,839,360 : total      (1,024)
  //   1,840,384 : bucketBase (1,024)
  //   1,841,408 : deg        (400,000)     -> 2,241,408
  //   2,241,408 : offset     (400,000)     -> 2,641,408
  //   2,641,408 : pairs      (6,406,144)   -> 9,047,552   (tile-major)
  //   9,047,552 : csr        (6,400,000)   -> 15,447,552
  //  15,447,552 : w1c bf16   (32,768)      -> 15,480,320
  //  15,480,320 : w2c bf16   (32,768)      -> 15,513,088
  //  15,513,088 : bn  fp32   (2,048)       -> 15,515,136
  //  15,515,136 : xb  bf16   (12,800,000)  -> 28,315,136
  //  28,315,136 : aggB bf16  (12,800,000)  -> 41,115,136
  //  41,115,136 : t   bf16   (12,800,000)  -> 53,915,136
  //  53,915,136 : r2  bf16   (12,800,000)  -> 66,715,136  (~67 MB)
  int*            tileCnt    = (int*)ws;
  int*            tileLo     = (int*)(ws + 613120);
  int*            colBase    = (int*)(ws + 1226240);
  int*            total      = (int*)(ws + 1839360);
  int*            bucketBase = (int*)(ws + 1840384);
  int*            deg        = (int*)(ws + 1841408);
  int*            offset     = (int*)(ws + 2241408);
  unsigned*       pairs      = (unsigned*)(ws + 2641408);
  int*            csr        = (int*)(ws + 9047552);
  unsigned short* w1c        = (unsigned short*)(ws + 15447552);
  unsigned short* w2c        = (unsigned short*)(ws + 15480320);
  float*          bn         = (float*)(ws + 15513088);
  unsigned short* xb         = (unsigned short*)(ws + 15515136);
  unsigned short* aggB       = (unsigned short*)(ws + 28315136);
  unsigned short* t          = (unsigned short*)(ws + 41115136);
  unsigned short* r2         = (unsigned short*)(ws + 53915136);

  const int* srcp = ei;
  const int* dstp = ei + NE;

  hipLaunchKernelGGL(k_prep, dim3(NN * 64 / 1024), dim3(256), 0, stream,
                     x, xb, w1l, w1r, w2l, w2r, b1l, g1, be1, m1, v1,
                     b2l, g2, be2, m2, v2, w1c, w2c, bn);
  hipLaunchKernelGGL(k_bin, dim3(NTIL), dim3(256), 0, stream,
                     srcp, dstp, pairs, tileCnt, tileLo);
  hipLaunchKernelGGL(k_colscan, dim3(NBUK), dim3(256), 0, stream,
                     tileCnt, colBase, total);
  hipLaunchKernelGGL(k_bscan, dim3(1), dim3(256), 0, stream, total, bucketBase);
  hipLaunchKernelGGL(k_build, dim3(NBUK), dim3(512), 0, stream,
                     pairs, tileLo, colBase, total, bucketBase, deg, offset, csr);
  hipLaunchKernelGGL(k_aggregate, dim3(NN / 32), dim3(256), 0, stream,
                     xb, deg, offset, csr, aggB);
  hipLaunchKernelGGL(k_gemm12, dim3((NN / 32 + 7) / 8), dim3(512), 0, stream,
                     aggB, xb, w1c, w2c, bn, t, r2);
  hipLaunchKernelGGL(k_agg2fin, dim3(NN / 32), dim3(256), 0, stream,
                     t, deg, offset, csr, r2, bn, outp);
}

// Round 15
// 134.470 us; speedup vs baseline: 1.3572x; 1.0071x over previous
//
#include <hip/hip_runtime.h>

#define NN 100000
#define NE 1600000
#define EPSV 1e-5f

#define NBUK 196       // buckets of 512 nodes: bucket = dst >> 9
#define TILE 2048      // edges per k_bin tile
#define NTIL 782       // ceil(NE / TILE); last tile has 512 edges
#define CAP  9216      // per-bucket capacity (mean 8163, sigma ~90 -> +11 sigma)

typedef __attribute__((ext_vector_type(8))) short bf16x8;
typedef __attribute__((ext_vector_type(4))) float f32x4;

__device__ inline unsigned short f2bf(float f) {
  unsigned u = __builtin_bit_cast(unsigned, f);
  unsigned r = u + 0x7FFFu + ((u >> 16) & 1u);
  return (unsigned short)(r >> 16);
}
__device__ inline float bf2f(unsigned short s) {
  unsigned u = ((unsigned)s) << 16;
  return __builtin_bit_cast(float, u);
}

// async global->LDS, 16B per lane; LDS dest = wave-uniform base + lane*16
__device__ __forceinline__ void gload_lds16(const unsigned short* g, unsigned short* l) {
  __builtin_amdgcn_global_load_lds(
      (const __attribute__((address_space(1))) void*)g,
      (__attribute__((address_space(3))) void*)l, 16, 0, 0);
}

// ---------------- phase 1: per-tile LDS bucket-sort, register-staged, 1 global pass ----------------
__global__ __launch_bounds__(256) void k_bin(const int* __restrict__ src,
                                             const int* __restrict__ dst,
                                             unsigned* __restrict__ pairs,
                                             int* __restrict__ tileCnt,
                                             int* __restrict__ tileLo) {
  __shared__ int cnt[NBUK];
  __shared__ int lo[NBUK];
  __shared__ int ts[256];
  __shared__ unsigned stage[TILE];
  const int tid = threadIdx.x;
  const int t = blockIdx.x;
  const int e0 = t * TILE;
  const int m = min(TILE, NE - e0);

  // single coalesced read of this tile's edges into registers
  int dreg[8], sreg[8];
#pragma unroll
  for (int u = 0; u < 8; ++u) {
    int i = u * 256 + tid;
    if (i < m) {
      dreg[u] = dst[e0 + i];
      sreg[u] = src[e0 + i];
    } else {
      dreg[u] = -1;
    }
  }

  for (int i = tid; i < NBUK; i += 256) cnt[i] = 0;
  __syncthreads();
#pragma unroll
  for (int u = 0; u < 8; ++u) {
    if (dreg[u] >= 0) atomicAdd(&cnt[dreg[u] >> 9], 1);
  }
  __syncthreads();
  int c = (tid < NBUK) ? cnt[tid] : 0;
  ts[tid] = c;
  __syncthreads();
  for (int d = 1; d < 256; d <<= 1) {
    int v = (tid >= d) ? ts[tid - d] : 0;
    __syncthreads();
    ts[tid] += v;
    __syncthreads();
  }
  if (tid < NBUK) {
    int ex = ts[tid] - c;
    lo[tid] = ex;
    cnt[tid] = ex;
  }
  __syncthreads();
#pragma unroll
  for (int u = 0; u < 8; ++u) {
    if (dreg[u] >= 0) {
      int pos = atomicAdd(&cnt[dreg[u] >> 9], 1);
      stage[pos] = ((unsigned)(dreg[u] & 511) << 17) | (unsigned)sreg[u];
    }
  }
  __syncthreads();
  for (int i = tid; i < m; i += 256) pairs[(size_t)t * TILE + i] = stage[i];
  if (tid < NBUK) {
    tileCnt[t * NBUK + tid] = cnt[tid] - lo[tid];
    tileLo[t * NBUK + tid] = lo[tid];
  }
}

// ---------------- phase 1.5a: per-bucket prefix over tiles ----------------
__global__ __launch_bounds__(256) void k_colscan(const int* __restrict__ tileCnt,
                                                 int* __restrict__ colBase,
                                                 int* __restrict__ total) {
  __shared__ int ts[256];
  const int tid = threadIdx.x;
  const int b = blockIdx.x;
  int v[4];
  int s = 0;
#pragma unroll
  for (int j = 0; j < 4; ++j) {
    int tt = tid * 4 + j;
    v[j] = (tt < NTIL) ? tileCnt[tt * NBUK + b] : 0;
    s += v[j];
  }
  ts[tid] = s;
  __syncthreads();
  for (int d = 1; d < 256; d <<= 1) {
    int x = (tid >= d) ? ts[tid - d] : 0;
    __syncthreads();
    ts[tid] += x;
    __syncthreads();
  }
  int run = ts[tid] - s;
#pragma unroll
  for (int j = 0; j < 4; ++j) {
    int tt = tid * 4 + j;
    if (tt < NTIL) colBase[(size_t)b * NTIL + tt] = run;
    run += v[j];
  }
  if (tid == 255) total[b] = ts[255];
}

// ---------------- phase 1.5b: scan bucket totals ----------------
__global__ __launch_bounds__(256) void k_bscan(const int* __restrict__ total,
                                               int* __restrict__ bucketBase) {
  __shared__ int ts[256];
  const int tid = threadIdx.x;
  int c = (tid < NBUK) ? min(total[tid], CAP) : 0;
  ts[tid] = c;
  __syncthreads();
  for (int d = 1; d < 256; d <<= 1) {
    int v = (tid >= d) ? ts[tid - d] : 0;
    __syncthreads();
    ts[tid] += v;
    __syncthreads();
  }
  if (tid < NBUK) bucketBase[tid] = ts[tid] - c;
}

// ---------------- phase 2: per-bucket CSR build via GATHER ----------------
__global__ __launch_bounds__(512) void k_build(const unsigned* __restrict__ pairs,
                                               const int* __restrict__ tileLo,
                                               const int* __restrict__ colBase,
                                               const int* __restrict__ total,
                                               const int* __restrict__ bucketBase,
                                               int* __restrict__ deg,
                                               int* __restrict__ offset,
                                               int* __restrict__ csr) {
  __shared__ unsigned stageA[CAP];
  __shared__ unsigned stageB[CAP];
  __shared__ int colB[NTIL];
  __shared__ int tLo[NTIL];
  __shared__ int hist[512];
  __shared__ int ts[512];
  const int tid = threadIdx.x;
  const int b = blockIdx.x;
  const int count = min(total[b], CAP);
  const int nbase = b * 512;
  const int nloc = min(512, NN - nbase);
  const int obase = bucketBase[b];

  for (int i = tid; i < NTIL; i += 512) {
    colB[i] = colBase[(size_t)b * NTIL + i];
    tLo[i] = tileLo[i * NBUK + b];
  }
  hist[tid] = 0;
  __syncthreads();
  for (int i = tid; i < count; i += 512) {
    int a = 0, z = NTIL - 1;
    while (a < z) {
      int mid = (a + z + 1) >> 1;
      if (colB[mid] <= i) a = mid; else z = mid - 1;
    }
    stageA[i] = pairs[(size_t)a * TILE + tLo[a] + (i - colB[a])];
  }
  __syncthreads();
  for (int i = tid; i < count; i += 512) {
    atomicAdd(&hist[stageA[i] >> 17], 1);
  }
  __syncthreads();
  int s = hist[tid];
  ts[tid] = s;
  __syncthreads();
  for (int d = 1; d < 512; d <<= 1) {
    int v = (tid >= d) ? ts[tid - d] : 0;
    __syncthreads();
    ts[tid] += v;
    __syncthreads();
  }
  int ex = ts[tid] - s;
  if (tid < nloc) {
    deg[nbase + tid] = s;
    offset[nbase + tid] = obase + ex;
  }
  hist[tid] = ex;
  __syncthreads();
  for (int i = tid; i < count; i += 512) {
    unsigned e = stageA[i];
    int pos = atomicAdd(&hist[e >> 17], 1);
    stageB[pos] = e & 0x1FFFFu;
  }
  __syncthreads();
  for (int i = tid; i < count; i += 512) csr[obase + i] = (int)stageB[i];
}

// ---------------- fused prep: x->bf16 + weights/BN ----------------
__global__ __launch_bounds__(256) void k_prep(const float* __restrict__ x,
                                              unsigned short* __restrict__ xb,
                                              const float* __restrict__ w1l,
                                              const float* __restrict__ w1r,
                                              const float* __restrict__ w2l,
                                              const float* __restrict__ w2r,
                                              const float* __restrict__ b1l,
                                              const float* __restrict__ g1,
                                              const float* __restrict__ be1,
                                              const float* __restrict__ m1,
                                              const float* __restrict__ v1,
                                              const float* __restrict__ b2l,
                                              const float* __restrict__ g2,
                                              const float* __restrict__ be2,
                                              const float* __restrict__ m2,
                                              const float* __restrict__ v2,
                                              unsigned short* __restrict__ w1c,
                                              unsigned short* __restrict__ w2c,
                                              float* __restrict__ bn) {
  int gi = blockIdx.x * 256 + threadIdx.x;
  float4 v = *(const float4*)(x + (size_t)gi * 4);
  ushort4 o;
  o.x = f2bf(v.x); o.y = f2bf(v.y); o.z = f2bf(v.z); o.w = f2bf(v.w);
  *(ushort4*)(xb + (size_t)gi * 4) = o;
  if (blockIdx.x < 64) {
    int i = gi;  // 0..16383
    int oo = i >> 7, k = i & 127;
    float vv1 = (k < 64) ? w1l[oo * 64 + k] : w1r[oo * 64 + (k - 64)];
    w1c[i] = f2bf(vv1);
    float vv2 = (oo < 64) ? w2l[oo * 128 + k] : w2r[(oo - 64) * 128 + k];
    w2c[i] = f2bf(vv2);
    if (i < 128) {
      float sc = g1[i] * rsqrtf(v1[i] + EPSV);
      bn[i] = sc;
      bn[128 + i] = (b1l[i] - m1[i]) * sc + be1[i];
    }
    if (i < 64) {
      float sc = g2[i] * rsqrtf(v2[i] + EPSV);
      bn[256 + i] = sc;
      bn[320 + i] = (b2l[i] - m2[i]) * sc + be2[i];
    }
  }
}

// ---------------- mean-aggregate: 8 lanes/node, 8-deep unrolled gather ----------------
__global__ __launch_bounds__(256) void k_aggregate(const unsigned short* __restrict__ xb,
                                                   const int* __restrict__ deg,
                                                   const int* __restrict__ offset,
                                                   const int* __restrict__ csr,
                                                   unsigned short* __restrict__ aggB) {
  int tid = threadIdx.x;
  int node = blockIdx.x * 32 + (tid >> 3);
  int j = tid & 7;
  int cnt = deg[node];
  const int* arow = csr + offset[node];
  float a0=0.f,a1=0.f,a2=0.f,a3=0.f,a4=0.f,a5=0.f,a6=0.f,a7=0.f;
  int k = 0;
  for (; k + 8 <= cnt; k += 8) {
    int s[8];
#pragma unroll
    for (int u = 0; u < 8; ++u) s[u] = arow[k + u];
    uint4 v[8];
#pragma unroll
    for (int u = 0; u < 8; ++u) v[u] = *(const uint4*)(xb + (size_t)s[u] * 64 + j * 8);
#pragma unroll
    for (int u = 0; u < 8; ++u) {
      a0 += bf2f(v[u].x & 0xffff); a1 += bf2f(v[u].x >> 16);
      a2 += bf2f(v[u].y & 0xffff); a3 += bf2f(v[u].y >> 16);
      a4 += bf2f(v[u].z & 0xffff); a5 += bf2f(v[u].z >> 16);
      a6 += bf2f(v[u].w & 0xffff); a7 += bf2f(v[u].w >> 16);
    }
  }
  if (k + 4 <= cnt) {
    int s[4];
#pragma unroll
    for (int u = 0; u < 4; ++u) s[u] = arow[k + u];
    uint4 v[4];
#pragma unroll
    for (int u = 0; u < 4; ++u) v[u] = *(const uint4*)(xb + (size_t)s[u] * 64 + j * 8);
#pragma unroll
    for (int u = 0; u < 4; ++u) {
      a0 += bf2f(v[u].x & 0xffff); a1 += bf2f(v[u].x >> 16);
      a2 += bf2f(v[u].y & 0xffff); a3 += bf2f(v[u].y >> 16);
      a4 += bf2f(v[u].z & 0xffff); a5 += bf2f(v[u].z >> 16);
      a6 += bf2f(v[u].w & 0xffff); a7 += bf2f(v[u].w >> 16);
    }
    k += 4;
  }
  for (; k < cnt; ++k) {
    int s = arow[k];
    uint4 v = *(const uint4*)(xb + (size_t)s * 64 + j * 8);
    a0 += bf2f(v.x & 0xffff); a1 += bf2f(v.x >> 16);
    a2 += bf2f(v.y & 0xffff); a3 += bf2f(v.y >> 16);
    a4 += bf2f(v.z & 0xffff); a5 += bf2f(v.z >> 16);
    a6 += bf2f(v.w & 0xffff); a7 += bf2f(v.w >> 16);
  }
  float inv = 1.0f / fmaxf((float)cnt, 1.0f);
  ushort4 r0, r1;
  r0.x = f2bf(a0 * inv); r0.y = f2bf(a1 * inv); r0.z = f2bf(a2 * inv); r0.w = f2bf(a3 * inv);
  r1.x = f2bf(a4 * inv); r1.y = f2bf(a5 * inv); r1.z = f2bf(a6 * inv); r1.w = f2bf(a7 * inv);
  *(ushort4*)(aggB + (size_t)node * 64 + j * 8) = r0;
  *(ushort4*)(aggB + (size_t)node * 64 + j * 8 + 4) = r1;
}

// ---------------- fused MFMA: weight-stationary, async staging, 1 barrier ----------------
__global__ __launch_bounds__(512, 1) void k_gemm12(const unsigned short* __restrict__ aggB,
                                                   const unsigned short* __restrict__ xb,
                                                   const unsigned short* __restrict__ w1c,
                                                   const unsigned short* __restrict__ w2c,
                                                   const float* __restrict__ bn,
                                                   unsigned short* __restrict__ t,
                                                   unsigned short* __restrict__ r2) {
  __shared__ unsigned short w1lds[32 * 512];      // 32KB fragment-major
  __shared__ unsigned short w2lds[32 * 512];      // 32KB fragment-major
  __shared__ unsigned short hlds[8][2][16 * 128]; // 64KB
  __shared__ float bnlds[384];                    // 1.5KB
  const int tid = threadIdx.x;
  const int w = tid >> 6;
  const int lane = tid & 63;
  const int lr = lane & 15;
  const int q = lane >> 4;
  const int tile = blockIdx.x * 8 + w;
  const int base = tile * 32;
  const int nA = base + lr, nB = base + 16 + lr;
  const int cA = min(nA, NN - 1), cB = min(nB, NN - 1);
  const int swz = (lr & 7) << 4;

#pragma unroll
  for (int it = 0; it < 4; ++it) {
    int idx = it * 512 + tid;
    int f = idx >> 6, l = idx & 63;
    int gofs = ((f >> 2) * 16 + (l & 15)) * 128 + (f & 3) * 32 + (l >> 4) * 8;
    gload_lds16(w1c + gofs, &w1lds[(it * 512 + w * 64) * 8]);
    gload_lds16(w2c + gofs, &w2lds[(it * 512 + w * 64) * 8]);
  }
  if (tid < 384) bnlds[tid] = bn[tid];

  bf16x8 fA[4], fB[4];
  {
    const unsigned short* a = aggB + (size_t)cA * 64 + q * 8;
    const unsigned short* xx = xb + (size_t)cA * 64 + q * 8;
    fA[0] = *(const bf16x8*)a;        fA[1] = *(const bf16x8*)(a + 32);
    fA[2] = *(const bf16x8*)xx;       fA[3] = *(const bf16x8*)(xx + 32);
  }
  {
    const unsigned short* a = aggB + (size_t)cB * 64 + q * 8;
    const unsigned short* xx = xb + (size_t)cB * 64 + q * 8;
    fB[0] = *(const bf16x8*)a;        fB[1] = *(const bf16x8*)(a + 32);
    fB[2] = *(const bf16x8*)xx;       fB[3] = *(const bf16x8*)(xx + 32);
  }
  __syncthreads();
  if (base >= NN) return;

  char* ldsA = (char*)&hlds[w][0][0];
  char* ldsB = (char*)&hlds[w][1][0];

#pragma unroll
  for (int ot = 0; ot < 8; ++ot) {
    const unsigned short* wp = &w1lds[(ot * 4) * 512 + lane * 8];
    bf16x8 w0 = *(const bf16x8*)(wp);
    bf16x8 w1 = *(const bf16x8*)(wp + 512);
    bf16x8 w2 = *(const bf16x8*)(wp + 1024);
    bf16x8 w3 = *(const bf16x8*)(wp + 1536);
    f32x4 aA = {0.f, 0.f, 0.f, 0.f}, aB = {0.f, 0.f, 0.f, 0.f};
    aA = __builtin_amdgcn_mfma_f32_16x16x32_bf16(w0, fA[0], aA, 0, 0, 0);
    aA = __builtin_amdgcn_mfma_f32_16x16x32_bf16(w1, fA[1], aA, 0, 0, 0);
    aA = __builtin_amdgcn_mfma_f32_16x16x32_bf16(w2, fA[2], aA, 0, 0, 0);
    aA = __builtin_amdgcn_mfma_f32_16x16x32_bf16(w3, fA[3], aA, 0, 0, 0);
    aB = __builtin_amdgcn_mfma_f32_16x16x32_bf16(w0, fB[0], aB, 0, 0, 0);
    aB = __builtin_amdgcn_mfma_f32_16x16x32_bf16(w1, fB[1], aB, 0, 0, 0);
    aB = __builtin_amdgcn_mfma_f32_16x16x32_bf16(w2, fB[2], aB, 0, 0, 0);
    aB = __builtin_amdgcn_mfma_f32_16x16x32_bf16(w3, fB[3], aB, 0, 0, 0);
    const int o = ot * 16 + q * 4;
    float4 sc = *(const float4*)&bnlds[o];
    float4 sh = *(const float4*)&bnlds[128 + o];
    ushort4 hA, hB;
    hA.x = f2bf(fmaxf(aA[0] * sc.x + sh.x, 0.f));
    hA.y = f2bf(fmaxf(aA[1] * sc.y + sh.y, 0.f));
    hA.z = f2bf(fmaxf(aA[2] * sc.z + sh.z, 0.f));
    hA.w = f2bf(fmaxf(aA[3] * sc.w + sh.w, 0.f));
    hB.x = f2bf(fmaxf(aB[0] * sc.x + sh.x, 0.f));
    hB.y = f2bf(fmaxf(aB[1] * sc.y + sh.y, 0.f));
    hB.z = f2bf(fmaxf(aB[2] * sc.z + sh.z, 0.f));
    hB.w = f2bf(fmaxf(aB[3] * sc.w + sh.w, 0.f));
    const int wb = lr * 256 + ot * 32 + q * 8;
    *(ushort4*)(ldsA + (wb ^ swz)) = hA;
    *(ushort4*)(ldsB + (wb ^ swz)) = hB;
  }

  bf16x8 hA[4], hB[4];
#pragma unroll
  for (int jj = 0; jj < 4; ++jj) {
    const int rb = lr * 256 + jj * 64 + q * 16;
    hA[jj] = *(const bf16x8*)(ldsA + (rb ^ swz));
    hB[jj] = *(const bf16x8*)(ldsB + (rb ^ swz));
  }

#pragma unroll
  for (int ot = 0; ot < 8; ++ot) {
    const unsigned short* wp = &w2lds[(ot * 4) * 512 + lane * 8];
    bf16x8 w0 = *(const bf16x8*)(wp);
    bf16x8 w1 = *(const bf16x8*)(wp + 512);
    bf16x8 w2 = *(const bf16x8*)(wp + 1024);
    bf16x8 w3 = *(const bf16x8*)(wp + 1536);
    f32x4 aA = {0.f, 0.f, 0.f, 0.f}, aB = {0.f, 0.f, 0.f, 0.f};
    aA = __builtin_amdgcn_mfma_f32_16x16x32_bf16(w0, hA[0], aA, 0, 0, 0);
    aA = __builtin_amdgcn_mfma_f32_16x16x32_bf16(w1, hA[1], aA, 0, 0, 0);
    aA = __builtin_amdgcn_mfma_f32_16x16x32_bf16(w2, hA[2], aA, 0, 0, 0);
    aA = __builtin_amdgcn_mfma_f32_16x16x32_bf16(w3, hA[3], aA, 0, 0, 0);
    aB = __builtin_amdgcn_mfma_f32_16x16x32_bf16(w0, hB[0], aB, 0, 0, 0);
    aB = __builtin_amdgcn_mfma_f32_16x16x32_bf16(w1, hB[1], aB, 0, 0, 0);
    aB = __builtin_amdgcn_mfma_f32_16x16x32_bf16(w2, hB[2], aB, 0, 0, 0);
    aB = __builtin_amdgcn_mfma_f32_16x16x32_bf16(w3, hB[3], aB, 0, 0, 0);
    ushort4 tv;
    if (ot < 4) {
      const int o = ot * 16 + q * 4;
      tv.x = f2bf(aA[0]); tv.y = f2bf(aA[1]); tv.z = f2bf(aA[2]); tv.w = f2bf(aA[3]);
      if (nA < NN) *(ushort4*)(t + (size_t)nA * 64 + o) = tv;
      tv.x = f2bf(aB[0]); tv.y = f2bf(aB[1]); tv.z = f2bf(aB[2]); tv.w = f2bf(aB[3]);
      if (nB < NN) *(ushort4*)(t + (size_t)nB * 64 + o) = tv;
    } else {
      const int o = (ot - 4) * 16 + q * 4;
      tv.x = f2bf(aA[0]); tv.y = f2bf(aA[1]); tv.z = f2bf(aA[2]); tv.w = f2bf(aA[3]);
      if (nA < NN) *(ushort4*)(r2 + (size_t)nA * 64 + o) = tv;
      tv.x = f2bf(aB[0]); tv.y = f2bf(aB[1]); tv.z = f2bf(aB[2]); tv.w = f2bf(aB[3]);
      if (nB < NN) *(ushort4*)(r2 + (size_t)nB * 64 + o) = tv;
    }
  }
}

// ---------------- layer2 aggregate + BN2: 8 lanes/node, 8-deep unrolled gather ----------------
__global__ __launch_bounds__(256) void k_agg2fin(const unsigned short* __restrict__ t,
                                                 const int* __restrict__ deg,
                                                 const int* __restrict__ offset,
                                                 const int* __restrict__ csr,
                                                 const unsigned short* __restrict__ r2,
                                                 const float* __restrict__ bn,
                                                 float* __restrict__ outp) {
  int tid = threadIdx.x;
  int node = blockIdx.x * 32 + (tid >> 3);
  int j = tid & 7;
  int cnt = deg[node];
  const int* arow = csr + offset[node];
  float a0=0.f,a1=0.f,a2=0.f,a3=0.f,a4=0.f,a5=0.f,a6=0.f,a7=0.f;
  int k = 0;
  for (; k + 8 <= cnt; k += 8) {
    int s[8];
#pragma unroll
    for (int u = 0; u < 8; ++u) s[u] = arow[k + u];
    uint4 v[8];
#pragma unroll
    for (int u = 0; u < 8; ++u) v[u] = *(const uint4*)(t + (size_t)s[u] * 64 + j * 8);
#pragma unroll
    for (int u = 0; u < 8; ++u) {
      a0 += bf2f(v[u].x & 0xffff); a1 += bf2f(v[u].x >> 16);
      a2 += bf2f(v[u].y & 0xffff); a3 += bf2f(v[u].y >> 16);
      a4 += bf2f(v[u].z & 0xffff); a5 += bf2f(v[u].z >> 16);
      a6 += bf2f(v[u].w & 0xffff); a7 += bf2f(v[u].w >> 16);
    }
  }
  if (k + 4 <= cnt) {
    int s[4];
#pragma unroll
    for (int u = 0; u < 4; ++u) s[u] = arow[k + u];
    uint4 v[4];
#pragma unroll
    for (int u = 0; u < 4; ++u) v[u] = *(const uint4*)(t + (size_t)s[u] * 64 + j * 8);
#pragma unroll
    for (int u = 0; u < 4; ++u) {
      a0 += bf2f(v[u].x & 0xffff); a1 += bf2f(v[u].x >> 16);
      a2 += bf2f(v[u].y & 0xffff); a3 += bf2f(v[u].y >> 16);
      a4 += bf2f(v[u].z & 0xffff); a5 += bf2f(v[u].z >> 16);
      a6 += bf2f(v[u].w & 0xffff); a7 += bf2f(v[u].w >> 16);
    }
    k += 4;
  }
  for (; k < cnt; ++k) {
    int s = arow[k];
    uint4 v = *(const uint4*)(t + (size_t)s * 64 + j * 8);
    a0 += bf2f(v.x & 0xffff); a1 += bf2f(v.x >> 16);
    a2 += bf2f(v.y & 0xffff); a3 += bf2f(v.y >> 16);
    a4 += bf2f(v.z & 0xffff); a5 += bf2f(v.z >> 16);
    a6 += bf2f(v.w & 0xffff); a7 += bf2f(v.w >> 16);
  }
  float inv = 1.0f / fmaxf((float)cnt, 1.0f);
  int o = j * 8;
  uint4 rv = *(const uint4*)(r2 + (size_t)node * 64 + o);
  float r0 = bf2f(rv.x & 0xffff), r1 = bf2f(rv.x >> 16);
  float r2a = bf2f(rv.y & 0xffff), r3 = bf2f(rv.y >> 16);
  float r4 = bf2f(rv.z & 0xffff), r5 = bf2f(rv.z >> 16);
  float r6 = bf2f(rv.w & 0xffff), r7 = bf2f(rv.w >> 16);
  float4 sca = *(const float4*)(bn + 256 + o);
  float4 scb = *(const float4*)(bn + 256 + o + 4);
  float4 sha = *(const float4*)(bn + 320 + o);
  float4 shb = *(const float4*)(bn + 320 + o + 4);
  float4 o0, o1;
  o0.x = (a0 * inv + r0) * sca.x + sha.x;
  o0.y = (a1 * inv + r1) * sca.y + sha.y;
  o0.z = (a2 * inv + r2a) * sca.z + sha.z;
  o0.w = (a3 * inv + r3) * sca.w + sha.w;
  o1.x = (a4 * inv + r4) * scb.x + shb.x;
  o1.y = (a5 * inv + r5) * scb.y + shb.y;
  o1.z = (a6 * inv + r6) * scb.z + shb.z;
  o1.w = (a7 * inv + r7) * scb.w + shb.w;
  *(float4*)(outp + (size_t)node * 64 + o) = o0;
  *(float4*)(outp + (size_t)node * 64 + o + 4) = o1;
}

extern "C" void kernel_launch(void* const* d_in, const int* in_sizes, int n_in,
                              void* d_out, int out_size, void* d_ws, size_t ws_size,
                              hipStream_t stream) {
  const float* x   = (const float*)d_in[0];
  const int*   ei  = (const int*)d_in[1];
  const float* w1l = (const float*)d_in[2];
  const float* b1l = (const float*)d_in[3];
  const float* w1r = (const float*)d_in[4];
  const float* g1  = (const float*)d_in[5];
  const float* be1 = (const float*)d_in[6];
  const float* m1  = (const float*)d_in[7];
  const float* v1  = (const float*)d_in[8];
  const float* w2l = (const float*)d_in[9];
  const float* b2l = (const float*)d_in[10];
  const float* w2r = (const float*)d_in[11];
  const float* g2  = (const float*)d_in[12];
  const float* be2 = (const float*)d_in[13];
  const float* m2  = (const float*)d_in[14];
  const float* v2  = (const float*)d_in[15];
  float* outp = (float*)d_out;

  char* ws = (char*)d_ws;
  // layout (bytes), 16B-aligned:
  //           0 : tileCnt    (613,120)     [782][196]
  //     613,120 : tileLo     (613,120)     [782][196]
  //   1,226,240 : colBase    (613,120)     [196][782]
  //   1,839,360 : total      (1,024)
  //   1,840,384 : bucketBase (1,024)
  //   1,841,408 : deg        (400,000)     -> 2,241,408
  //   2,241,408 : offset     (400,000)     -> 2,641,408
  //   2,641,408 : pairs      (6,406,144)   -> 9,047,552   (tile-major)
  //   9,047,552 : csr        (6,400,000)   -> 15,447,552
  //  15,447,552 : w1c bf16   (32,768)      -> 15,480,320
  //  15,480,320 : w2c bf16   (32,768)      -> 15,513,088
  //  15,513,088 : bn  fp32   (2,048)       -> 15,515,136
  //  15,515,136 : xb  bf16   (12,800,000)  -> 28,315,136
  //  28,315,136 : aggB bf16  (12,800,000)  -> 41,115,136
  //  41,115,136 : t   bf16   (12,800,000)  -> 53,915,136
  //  53,915,136 : r2  bf16   (12,800,000)  -> 66,715,136  (~67 MB)
  int*            tileCnt    = (int*)ws;
  int*            tileLo     = (int*)(ws + 613120);
  int*            colBase    = (int*)(ws + 1226240);
  int*            total      = (int*)(ws + 1839360);
  int*            bucketBase = (int*)(ws + 1840384);
  int*            deg        = (int*)(ws + 1841408);
  int*            offset     = (int*)(ws + 2241408);
  unsigned*       pairs      = (unsigned*)(ws + 2641408);
  int*            csr        = (int*)(ws + 9047552);
  unsigned short* w1c        = (unsigned short*)(ws + 15447552);
  unsigned short* w2c        = (unsigned short*)(ws + 15480320);
  float*          bn         = (float*)(ws + 15513088);
  unsigned short* xb         = (unsigned short*)(ws + 15515136);
  unsigned short* aggB       = (unsigned short*)(ws + 28315136);
  unsigned short* t          = (unsigned short*)(ws + 41115136);
  unsigned short* r2         = (unsigned short*)(ws + 53915136);

  const int* srcp = ei;
  const int* dstp = ei + NE;

  hipLaunchKernelGGL(k_prep, dim3(NN * 64 / 1024), dim3(256), 0, stream,
                     x, xb, w1l, w1r, w2l, w2r, b1l, g1, be1, m1, v1,
                     b2l, g2, be2, m2, v2, w1c, w2c, bn);
  hipLaunchKernelGGL(k_bin, dim3(NTIL), dim3(256), 0, stream,
                     srcp, dstp, pairs, tileCnt, tileLo);
  hipLaunchKernelGGL(k_colscan, dim3(NBUK), dim3(256), 0, stream,
                     tileCnt, colBase, total);
  hipLaunchKernelGGL(k_bscan, dim3(1), dim3(256), 0, stream, total, bucketBase);
  hipLaunchKernelGGL(k_build, dim3(NBUK), dim3(512), 0, stream,
                     pairs, tileLo, colBase, total, bucketBase, deg, offset, csr);
  hipLaunchKernelGGL(k_aggregate, dim3(NN / 32), dim3(256), 0, stream,
                     xb, deg, offset, csr, aggB);
  hipLaunchKernelGGL(k_gemm12, dim3((NN / 32 + 7) / 8), dim3(512), 0, stream,
                     aggB, xb, w1c, w2c, bn, t, r2);
  hipLaunchKernelGGL(k_agg2fin, dim3(NN / 32), dim3(256), 0, stream,
                     t, deg, offset, csr, r2, bn, outp);
}

// Round 16
// 128.661 us; speedup vs baseline: 1.4185x; 1.0452x over previous
//
#include <hip/hip_runtime.h>

#define NN 100000
#define NE 1600000
#define EPSV 1e-5f

#define NBUK 196       // buckets of 512 nodes: bucket = dst >> 9
#define TILE 2048      // edges per k_bin tile
#define NTIL 782       // ceil(NE / TILE); last tile has 512 edges
#define NPREP 6250     // x-conversion blocks (6250*1024 floats = 6.4M)
#define CAP  9216      // per-bucket capacity (mean 8163, sigma ~90 -> +11 sigma)

typedef __attribute__((ext_vector_type(8))) short bf16x8;
typedef __attribute__((ext_vector_type(4))) float f32x4;

__device__ inline unsigned short f2bf(float f) {
  unsigned u = __builtin_bit_cast(unsigned, f);
  unsigned r = u + 0x7FFFu + ((u >> 16) & 1u);
  return (unsigned short)(r >> 16);
}
__device__ inline float bf2f(unsigned short s) {
  unsigned u = ((unsigned)s) << 16;
  return __builtin_bit_cast(float, u);
}

// async global->LDS, 16B per lane; LDS dest = wave-uniform base + lane*16
__device__ __forceinline__ void gload_lds16(const unsigned short* g, unsigned short* l) {
  __builtin_amdgcn_global_load_lds(
      (const __attribute__((address_space(1))) void*)g,
      (__attribute__((address_space(3))) void*)l, 16, 0, 0);
}

// ---------------- phase 1 (merged): blocks<NTIL = tile bucket-sort; rest = prep ----------------
__global__ __launch_bounds__(256) void k_binprep(const int* __restrict__ src,
                                                 const int* __restrict__ dst,
                                                 unsigned* __restrict__ pairs,
                                                 int* __restrict__ tileCnt,
                                                 int* __restrict__ tileLo,
                                                 const float* __restrict__ x,
                                                 unsigned short* __restrict__ xb,
                                                 const float* __restrict__ w1l,
                                                 const float* __restrict__ w1r,
                                                 const float* __restrict__ w2l,
                                                 const float* __restrict__ w2r,
                                                 const float* __restrict__ b1l,
                                                 const float* __restrict__ g1,
                                                 const float* __restrict__ be1,
                                                 const float* __restrict__ m1,
                                                 const float* __restrict__ v1,
                                                 const float* __restrict__ b2l,
                                                 const float* __restrict__ g2,
                                                 const float* __restrict__ be2,
                                                 const float* __restrict__ m2,
                                                 const float* __restrict__ v2,
                                                 unsigned short* __restrict__ w1c,
                                                 unsigned short* __restrict__ w2c,
                                                 float* __restrict__ bn) {
  const int tid = threadIdx.x;
  if (blockIdx.x >= NTIL) {
    // ---- prep section ----
    const int pb = blockIdx.x - NTIL;
    const int gi = pb * 256 + tid;
    float4 v = *(const float4*)(x + (size_t)gi * 4);
    ushort4 o;
    o.x = f2bf(v.x); o.y = f2bf(v.y); o.z = f2bf(v.z); o.w = f2bf(v.w);
    *(ushort4*)(xb + (size_t)gi * 4) = o;
    if (pb < 64) {
      int i = pb * 256 + tid;  // 0..16383
      int oo = i >> 7, k = i & 127;
      float vv1 = (k < 64) ? w1l[oo * 64 + k] : w1r[oo * 64 + (k - 64)];
      w1c[i] = f2bf(vv1);
      float vv2 = (oo < 64) ? w2l[oo * 128 + k] : w2r[(oo - 64) * 128 + k];
      w2c[i] = f2bf(vv2);
      if (i < 128) {
        float sc = g1[i] * rsqrtf(v1[i] + EPSV);
        bn[i] = sc;
        bn[128 + i] = (b1l[i] - m1[i]) * sc + be1[i];
      }
      if (i < 64) {
        float sc = g2[i] * rsqrtf(v2[i] + EPSV);
        bn[256 + i] = sc;
        bn[320 + i] = (b2l[i] - m2[i]) * sc + be2[i];
      }
    }
    return;
  }
  // ---- bin section ----
  __shared__ int cnt[NBUK];
  __shared__ int lo[NBUK];
  __shared__ int ts[256];
  __shared__ unsigned stage[TILE];
  const int t = blockIdx.x;
  const int e0 = t * TILE;
  const int m = min(TILE, NE - e0);

  int dreg[8], sreg[8];
#pragma unroll
  for (int u = 0; u < 8; ++u) {
    int i = u * 256 + tid;
    if (i < m) {
      dreg[u] = dst[e0 + i];
      sreg[u] = src[e0 + i];
    } else {
      dreg[u] = -1;
    }
  }

  for (int i = tid; i < NBUK; i += 256) cnt[i] = 0;
  __syncthreads();
#pragma unroll
  for (int u = 0; u < 8; ++u) {
    if (dreg[u] >= 0) atomicAdd(&cnt[dreg[u] >> 9], 1);
  }
  __syncthreads();
  int c = (tid < NBUK) ? cnt[tid] : 0;
  ts[tid] = c;
  __syncthreads();
  for (int d = 1; d < 256; d <<= 1) {
    int v = (tid >= d) ? ts[tid - d] : 0;
    __syncthreads();
    ts[tid] += v;
    __syncthreads();
  }
  if (tid < NBUK) {
    int ex = ts[tid] - c;
    lo[tid] = ex;
    cnt[tid] = ex;
  }
  __syncthreads();
#pragma unroll
  for (int u = 0; u < 8; ++u) {
    if (dreg[u] >= 0) {
      int pos = atomicAdd(&cnt[dreg[u] >> 9], 1);
      stage[pos] = ((unsigned)(dreg[u] & 511) << 17) | (unsigned)sreg[u];
    }
  }
  __syncthreads();
  for (int i = tid; i < m; i += 256) pairs[(size_t)t * TILE + i] = stage[i];
  if (tid < NBUK) {
    tileCnt[t * NBUK + tid] = cnt[tid] - lo[tid];
    tileLo[t * NBUK + tid] = lo[tid];
  }
}

// ---------------- phase 1.5: per-bucket prefix over tiles ----------------
__global__ __launch_bounds__(256) void k_colscan(const int* __restrict__ tileCnt,
                                                 int* __restrict__ colBase) {
  __shared__ int ts[256];
  const int tid = threadIdx.x;
  const int b = blockIdx.x;
  int v[4];
  int s = 0;
#pragma unroll
  for (int j = 0; j < 4; ++j) {
    int tt = tid * 4 + j;
    v[j] = (tt < NTIL) ? tileCnt[tt * NBUK + b] : 0;
    s += v[j];
  }
  ts[tid] = s;
  __syncthreads();
  for (int d = 1; d < 256; d <<= 1) {
    int x = (tid >= d) ? ts[tid - d] : 0;
    __syncthreads();
    ts[tid] += x;
    __syncthreads();
  }
  int run = ts[tid] - s;
#pragma unroll
  for (int j = 0; j < 4; ++j) {
    int tt = tid * 4 + j;
    if (tt < NTIL) colBase[(size_t)b * NTIL + tt] = run;
    run += v[j];
  }
}

// ---------------- phase 2: per-bucket CSR build via GATHER (self-computed bucketBase) ----------------
__global__ __launch_bounds__(512) void k_build(const unsigned* __restrict__ pairs,
                                               const int* __restrict__ tileCnt,
                                               const int* __restrict__ tileLo,
                                               const int* __restrict__ colBase,
                                               int* __restrict__ deg,
                                               int* __restrict__ offset,
                                               int* __restrict__ csr) {
  __shared__ unsigned stageA[CAP];
  __shared__ unsigned stageB[CAP];
  __shared__ int colB[NTIL];
  __shared__ int tLo[NTIL];
  __shared__ int hist[512];
  __shared__ int ts[512];
  __shared__ int obase_sh, count_sh;
  const int tid = threadIdx.x;
  const int b = blockIdx.x;
  const int nbase = b * 512;
  const int nloc = min(512, NN - nbase);

  // compute all bucket totals, scan -> own obase/count (replaces k_bscan)
  int tb = 0;
  if (tid < NBUK) {
    int cb = colBase[(size_t)tid * NTIL + (NTIL - 1)];
    int tc = tileCnt[(NTIL - 1) * NBUK + tid];
    tb = min(cb + tc, CAP);
  }
  ts[tid] = tb;
  __syncthreads();
  for (int d = 1; d < 512; d <<= 1) {
    int v = (tid >= d) ? ts[tid - d] : 0;
    __syncthreads();
    ts[tid] += v;
    __syncthreads();
  }
  if (tid == b) { obase_sh = ts[tid] - tb; count_sh = tb; }
  for (int i = tid; i < NTIL; i += 512) {
    colB[i] = colBase[(size_t)b * NTIL + i];
    tLo[i] = tileLo[i * NBUK + b];
  }
  hist[tid] = 0;
  __syncthreads();
  const int obase = obase_sh;
  const int count = count_sh;

  for (int i = tid; i < count; i += 512) {
    int a = 0, z = NTIL - 1;
    while (a < z) {
      int mid = (a + z + 1) >> 1;
      if (colB[mid] <= i) a = mid; else z = mid - 1;
    }
    stageA[i] = pairs[(size_t)a * TILE + tLo[a] + (i - colB[a])];
  }
  __syncthreads();
  for (int i = tid; i < count; i += 512) {
    atomicAdd(&hist[stageA[i] >> 17], 1);
  }
  __syncthreads();
  int s = hist[tid];
  ts[tid] = s;
  __syncthreads();
  for (int d = 1; d < 512; d <<= 1) {
    int v = (tid >= d) ? ts[tid - d] : 0;
    __syncthreads();
    ts[tid] += v;
    __syncthreads();
  }
  int ex = ts[tid] - s;
  if (tid < nloc) {
    deg[nbase + tid] = s;
    offset[nbase + tid] = obase + ex;
  }
  hist[tid] = ex;
  __syncthreads();
  for (int i = tid; i < count; i += 512) {
    unsigned e = stageA[i];
    int pos = atomicAdd(&hist[e >> 17], 1);
    stageB[pos] = e & 0x1FFFFu;
  }
  __syncthreads();
  for (int i = tid; i < count; i += 512) csr[obase + i] = (int)stageB[i];
}

// ---------------- mean-aggregate: 8 lanes/node, 8-deep unrolled gather ----------------
__global__ __launch_bounds__(256) void k_aggregate(const unsigned short* __restrict__ xb,
                                                   const int* __restrict__ deg,
                                                   const int* __restrict__ offset,
                                                   const int* __restrict__ csr,
                                                   unsigned short* __restrict__ aggB) {
  int tid = threadIdx.x;
  int node = blockIdx.x * 32 + (tid >> 3);
  int j = tid & 7;
  int cnt = deg[node];
  const int* arow = csr + offset[node];
  float a0=0.f,a1=0.f,a2=0.f,a3=0.f,a4=0.f,a5=0.f,a6=0.f,a7=0.f;
  int k = 0;
  for (; k + 8 <= cnt; k += 8) {
    int s[8];
#pragma unroll
    for (int u = 0; u < 8; ++u) s[u] = arow[k + u];
    uint4 v[8];
#pragma unroll
    for (int u = 0; u < 8; ++u) v[u] = *(const uint4*)(xb + (size_t)s[u] * 64 + j * 8);
#pragma unroll
    for (int u = 0; u < 8; ++u) {
      a0 += bf2f(v[u].x & 0xffff); a1 += bf2f(v[u].x >> 16);
      a2 += bf2f(v[u].y & 0xffff); a3 += bf2f(v[u].y >> 16);
      a4 += bf2f(v[u].z & 0xffff); a5 += bf2f(v[u].z >> 16);
      a6 += bf2f(v[u].w & 0xffff); a7 += bf2f(v[u].w >> 16);
    }
  }
  if (k + 4 <= cnt) {
    int s[4];
#pragma unroll
    for (int u = 0; u < 4; ++u) s[u] = arow[k + u];
    uint4 v[4];
#pragma unroll
    for (int u = 0; u < 4; ++u) v[u] = *(const uint4*)(xb + (size_t)s[u] * 64 + j * 8);
#pragma unroll
    for (int u = 0; u < 4; ++u) {
      a0 += bf2f(v[u].x & 0xffff); a1 += bf2f(v[u].x >> 16);
      a2 += bf2f(v[u].y & 0xffff); a3 += bf2f(v[u].y >> 16);
      a4 += bf2f(v[u].z & 0xffff); a5 += bf2f(v[u].z >> 16);
      a6 += bf2f(v[u].w & 0xffff); a7 += bf2f(v[u].w >> 16);
    }
    k += 4;
  }
  for (; k < cnt; ++k) {
    int s = arow[k];
    uint4 v = *(const uint4*)(xb + (size_t)s * 64 + j * 8);
    a0 += bf2f(v.x & 0xffff); a1 += bf2f(v.x >> 16);
    a2 += bf2f(v.y & 0xffff); a3 += bf2f(v.y >> 16);
    a4 += bf2f(v.z & 0xffff); a5 += bf2f(v.z >> 16);
    a6 += bf2f(v.w & 0xffff); a7 += bf2f(v.w >> 16);
  }
  float inv = 1.0f / fmaxf((float)cnt, 1.0f);
  ushort4 r0, r1;
  r0.x = f2bf(a0 * inv); r0.y = f2bf(a1 * inv); r0.z = f2bf(a2 * inv); r0.w = f2bf(a3 * inv);
  r1.x = f2bf(a4 * inv); r1.y = f2bf(a5 * inv); r1.z = f2bf(a6 * inv); r1.w = f2bf(a7 * inv);
  *(ushort4*)(aggB + (size_t)node * 64 + j * 8) = r0;
  *(ushort4*)(aggB + (size_t)node * 64 + j * 8 + 4) = r1;
}

// ---------------- fused MFMA: weight-stationary, async staging, 1 barrier ----------------
__global__ __launch_bounds__(512, 1) void k_gemm12(const unsigned short* __restrict__ aggB,
                                                   const unsigned short* __restrict__ xb,
                                                   const unsigned short* __restrict__ w1c,
                                                   const unsigned short* __restrict__ w2c,
                                                   const float* __restrict__ bn,
                                                   unsigned short* __restrict__ t,
                                                   unsigned short* __restrict__ r2) {
  __shared__ unsigned short w1lds[32 * 512];      // 32KB fragment-major
  __shared__ unsigned short w2lds[32 * 512];      // 32KB fragment-major
  __shared__ unsigned short hlds[8][2][16 * 128]; // 64KB
  __shared__ float bnlds[384];                    // 1.5KB
  const int tid = threadIdx.x;
  const int w = tid >> 6;
  const int lane = tid & 63;
  const int lr = lane & 15;
  const int q = lane >> 4;
  const int tile = blockIdx.x * 8 + w;
  const int base = tile * 32;
  const int nA = base + lr, nB = base + 16 + lr;
  const int cA = min(nA, NN - 1), cB = min(nB, NN - 1);
  const int swz = (lr & 7) << 4;

#pragma unroll
  for (int it = 0; it < 4; ++it) {
    int idx = it * 512 + tid;
    int f = idx >> 6, l = idx & 63;
    int gofs = ((f >> 2) * 16 + (l & 15)) * 128 + (f & 3) * 32 + (l >> 4) * 8;
    gload_lds16(w1c + gofs, &w1lds[(it * 512 + w * 64) * 8]);
    gload_lds16(w2c + gofs, &w2lds[(it * 512 + w * 64) * 8]);
  }
  if (tid < 384) bnlds[tid] = bn[tid];

  bf16x8 fA[4], fB[4];
  {
    const unsigned short* a = aggB + (size_t)cA * 64 + q * 8;
    const unsigned short* xx = xb + (size_t)cA * 64 + q * 8;
    fA[0] = *(const bf16x8*)a;        fA[1] = *(const bf16x8*)(a + 32);
    fA[2] = *(const bf16x8*)xx;       fA[3] = *(const bf16x8*)(xx + 32);
  }
  {
    const unsigned short* a = aggB + (size_t)cB * 64 + q * 8;
    const unsigned short* xx = xb + (size_t)cB * 64 + q * 8;
    fB[0] = *(const bf16x8*)a;        fB[1] = *(const bf16x8*)(a + 32);
    fB[2] = *(const bf16x8*)xx;       fB[3] = *(const bf16x8*)(xx + 32);
  }
  __syncthreads();
  if (base >= NN) return;

  char* ldsA = (char*)&hlds[w][0][0];
  char* ldsB = (char*)&hlds[w][1][0];

#pragma unroll
  for (int ot = 0; ot < 8; ++ot) {
    const unsigned short* wp = &w1lds[(ot * 4) * 512 + lane * 8];
    bf16x8 w0 = *(const bf16x8*)(wp);
    bf16x8 w1 = *(const bf16x8*)(wp + 512);
    bf16x8 w2 = *(const bf16x8*)(wp + 1024);
    bf16x8 w3 = *(const bf16x8*)(wp + 1536);
    f32x4 aA = {0.f, 0.f, 0.f, 0.f}, aB = {0.f, 0.f, 0.f, 0.f};
    aA = __builtin_amdgcn_mfma_f32_16x16x32_bf16(w0, fA[0], aA, 0, 0, 0);
    aA = __builtin_amdgcn_mfma_f32_16x16x32_bf16(w1, fA[1], aA, 0, 0, 0);
    aA = __builtin_amdgcn_mfma_f32_16x16x32_bf16(w2, fA[2], aA, 0, 0, 0);
    aA = __builtin_amdgcn_mfma_f32_16x16x32_bf16(w3, fA[3], aA, 0, 0, 0);
    aB = __builtin_amdgcn_mfma_f32_16x16x32_bf16(w0, fB[0], aB, 0, 0, 0);
    aB = __builtin_amdgcn_mfma_f32_16x16x32_bf16(w1, fB[1], aB, 0, 0, 0);
    aB = __builtin_amdgcn_mfma_f32_16x16x32_bf16(w2, fB[2], aB, 0, 0, 0);
    aB = __builtin_amdgcn_mfma_f32_16x16x32_bf16(w3, fB[3], aB, 0, 0, 0);
    const int o = ot * 16 + q * 4;
    float4 sc = *(const float4*)&bnlds[o];
    float4 sh = *(const float4*)&bnlds[128 + o];
    ushort4 hA, hB;
    hA.x = f2bf(fmaxf(aA[0] * sc.x + sh.x, 0.f));
    hA.y = f2bf(fmaxf(aA[1] * sc.y + sh.y, 0.f));
    hA.z = f2bf(fmaxf(aA[2] * sc.z + sh.z, 0.f));
    hA.w = f2bf(fmaxf(aA[3] * sc.w + sh.w, 0.f));
    hB.x = f2bf(fmaxf(aB[0] * sc.x + sh.x, 0.f));
    hB.y = f2bf(fmaxf(aB[1] * sc.y + sh.y, 0.f));
    hB.z = f2bf(fmaxf(aB[2] * sc.z + sh.z, 0.f));
    hB.w = f2bf(fmaxf(aB[3] * sc.w + sh.w, 0.f));
    const int wb = lr * 256 + ot * 32 + q * 8;
    *(ushort4*)(ldsA + (wb ^ swz)) = hA;
    *(ushort4*)(ldsB + (wb ^ swz)) = hB;
  }

  bf16x8 hA[4], hB[4];
#pragma unroll
  for (int jj = 0; jj < 4; ++jj) {
    const int rb = lr * 256 + jj * 64 + q * 16;
    hA[jj] = *(const bf16x8*)(ldsA + (rb ^ swz));
    hB[jj] = *(const bf16x8*)(ldsB + (rb ^ swz));
  }

#pragma unroll
  for (int ot = 0; ot < 8; ++ot) {
    const unsigned short* wp = &w2lds[(ot * 4) * 512 + lane * 8];
    bf16x8 w0 = *(const bf16x8*)(wp);
    bf16x8 w1 = *(const bf16x8*)(wp + 512);
    bf16x8 w2 = *(const bf16x8*)(wp + 1024);
    bf16x8 w3 = *(const bf16x8*)(wp + 1536);
    f32x4 aA = {0.f, 0.f, 0.f, 0.f}, aB = {0.f, 0.f, 0.f, 0.f};
    aA = __builtin_amdgcn_mfma_f32_16x16x32_bf16(w0, hA[0], aA, 0, 0, 0);
    aA = __builtin_amdgcn_mfma_f32_16x16x32_bf16(w1, hA[1], aA, 0, 0, 0);
    aA = __builtin_amdgcn_mfma_f32_16x16x32_bf16(w2, hA[2], aA, 0, 0, 0);
    aA = __builtin_amdgcn_mfma_f32_16x16x32_bf16(w3, hA[3], aA, 0, 0, 0);
    aB = __builtin_amdgcn_mfma_f32_16x16x32_bf16(w0, hB[0], aB, 0, 0, 0);
    aB = __builtin_amdgcn_mfma_f32_16x16x32_bf16(w1, hB[1], aB, 0, 0, 0);
    aB = __builtin_amdgcn_mfma_f32_16x16x32_bf16(w2, hB[2], aB, 0, 0, 0);
    aB = __builtin_amdgcn_mfma_f32_16x16x32_bf16(w3, hB[3], aB, 0, 0, 0);
    ushort4 tv;
    if (ot < 4) {
      const int o = ot * 16 + q * 4;
      tv.x = f2bf(aA[0]); tv.y = f2bf(aA[1]); tv.z = f2bf(aA[2]); tv.w = f2bf(aA[3]);
      if (nA < NN) *(ushort4*)(t + (size_t)nA * 64 + o) = tv;
      tv.x = f2bf(aB[0]); tv.y = f2bf(aB[1]); tv.z = f2bf(aB[2]); tv.w = f2bf(aB[3]);
      if (nB < NN) *(ushort4*)(t + (size_t)nB * 64 + o) = tv;
    } else {
      const int o = (ot - 4) * 16 + q * 4;
      tv.x = f2bf(aA[0]); tv.y = f2bf(aA[1]); tv.z = f2bf(aA[2]); tv.w = f2bf(aA[3]);
      if (nA < NN) *(ushort4*)(r2 + (size_t)nA * 64 + o) = tv;
      tv.x = f2bf(aB[0]); tv.y = f2bf(aB[1]); tv.z = f2bf(aB[2]); tv.w = f2bf(aB[3]);
      if (nB < NN) *(ushort4*)(r2 + (size_t)nB * 64 + o) = tv;
    }
  }
}

// ---------------- layer2 aggregate + BN2: 8 lanes/node, 8-deep unrolled gather ----------------
__global__ __launch_bounds__(256) void k_agg2fin(const unsigned short* __restrict__ t,
                                                 const int* __restrict__ deg,
                                                 const int* __restrict__ offset,
                                                 const int* __restrict__ csr,
                                                 const unsigned short* __restrict__ r2,
                                                 const float* __restrict__ bn,
                                                 float* __restrict__ outp) {
  int tid = threadIdx.x;
  int node = blockIdx.x * 32 + (tid >> 3);
  int j = tid & 7;
  int cnt = deg[node];
  const int* arow = csr + offset[node];
  float a0=0.f,a1=0.f,a2=0.f,a3=0.f,a4=0.f,a5=0.f,a6=0.f,a7=0.f;
  int k = 0;
  for (; k + 8 <= cnt; k += 8) {
    int s[8];
#pragma unroll
    for (int u = 0; u < 8; ++u) s[u] = arow[k + u];
    uint4 v[8];
#pragma unroll
    for (int u = 0; u < 8; ++u) v[u] = *(const uint4*)(t + (size_t)s[u] * 64 + j * 8);
#pragma unroll
    for (int u = 0; u < 8; ++u) {
      a0 += bf2f(v[u].x & 0xffff); a1 += bf2f(v[u].x >> 16);
      a2 += bf2f(v[u].y & 0xffff); a3 += bf2f(v[u].y >> 16);
      a4 += bf2f(v[u].z & 0xffff); a5 += bf2f(v[u].z >> 16);
      a6 += bf2f(v[u].w & 0xffff); a7 += bf2f(v[u].w >> 16);
    }
  }
  if (k + 4 <= cnt) {
    int s[4];
#pragma unroll
    for (int u = 0; u < 4; ++u) s[u] = arow[k + u];
    uint4 v[4];
#pragma unroll
    for (int u = 0; u < 4; ++u) v[u] = *(const uint4*)(t + (size_t)s[u] * 64 + j * 8);
#pragma unroll
    for (int u = 0; u < 4; ++u) {
      a0 += bf2f(v[u].x & 0xffff); a1 += bf2f(v[u].x >> 16);
      a2 += bf2f(v[u].y & 0xffff); a3 += bf2f(v[u].y >> 16);
      a4 += bf2f(v[u].z & 0xffff); a5 += bf2f(v[u].z >> 16);
      a6 += bf2f(v[u].w & 0xffff); a7 += bf2f(v[u].w >> 16);
    }
    k += 4;
  }
  for (; k < cnt; ++k) {
    int s = arow[k];
    uint4 v = *(const uint4*)(t + (size_t)s * 64 + j * 8);
    a0 += bf2f(v.x & 0xffff); a1 += bf2f(v.x >> 16);
    a2 += bf2f(v.y & 0xffff); a3 += bf2f(v.y >> 16);
    a4 += bf2f(v.z & 0xffff); a5 += bf2f(v.z >> 16);
    a6 += bf2f(v.w & 0xffff); a7 += bf2f(v.w >> 16);
  }
  float inv = 1.0f / fmaxf((float)cnt, 1.0f);
  int o = j * 8;
  uint4 rv = *(const uint4*)(r2 + (size_t)node * 64 + o);
  float r0 = bf2f(rv.x & 0xffff), r1 = bf2f(rv.x >> 16);
  float r2a = bf2f(rv.y & 0xffff), r3 = bf2f(rv.y >> 16);
  float r4 = bf2f(rv.z & 0xffff), r5 = bf2f(rv.z >> 16);
  float r6 = bf2f(rv.w & 0xffff), r7 = bf2f(rv.w >> 16);
  float4 sca = *(const float4*)(bn + 256 + o);
  float4 scb = *(const float4*)(bn + 256 + o + 4);
  float4 sha = *(const float4*)(bn + 320 + o);
  float4 shb = *(const float4*)(bn + 320 + o + 4);
  float4 o0, o1;
  o0.x = (a0 * inv + r0) * sca.x + sha.x;
  o0.y = (a1 * inv + r1) * sca.y + sha.y;
  o0.z = (a2 * inv + r2a) * sca.z + sha.z;
  o0.w = (a3 * inv + r3) * sca.w + sha.w;
  o1.x = (a4 * inv + r4) * scb.x + shb.x;
  o1.y = (a5 * inv + r5) * scb.y + shb.y;
  o1.z = (a6 * inv + r6) * scb.z + shb.z;
  o1.w = (a7 * inv + r7) * scb.w + shb.w;
  *(float4*)(outp + (size_t)node * 64 + o) = o0;
  *(float4*)(outp + (size_t)node * 64 + o + 4) = o1;
}

extern "C" void kernel_launch(void* const* d_in, const int* in_sizes, int n_in,
                              void* d_out, int out_size, void* d_ws, size_t ws_size,
                              hipStream_t stream) {
  const float* x   = (const float*)d_in[0];
  const int*   ei  = (const int*)d_in[1];
  const float* w1l = (const float*)d_in[2];
  const float* b1l = (const float*)d_in[3];
  const float* w1r = (const float*)d_in[4];
  const float* g1  = (const float*)d_in[5];
  const float* be1 = (const float*)d_in[6];
  const float* m1  = (const float*)d_in[7];
  const float* v1  = (const float*)d_in[8];
  const float* w2l = (const float*)d_in[9];
  const float* b2l = (const float*)d_in[10];
  const float* w2r = (const float*)d_in[11];
  const float* g2  = (const float*)d_in[12];
  const float* be2 = (const float*)d_in[13];
  const float* m2  = (const float*)d_in[14];
  const float* v2  = (const float*)d_in[15];
  float* outp = (float*)d_out;

  char* ws = (char*)d_ws;
  // layout (bytes), 16B-aligned:
  //           0 : tileCnt    (613,120)     [782][196]
  //     613,120 : tileLo     (613,120)     [782][196]
  //   1,226,240 : colBase    (613,120)     [196][782]
  //   1,839,360 : deg        (400,000)     -> 2,239,360
  //   2,239,360 : offset     (400,000)     -> 2,639,360
  //   2,639,360 : pairs      (6,406,144)   -> 9,045,504   (tile-major)
  //   9,045,504 : csr        (6,400,000)   -> 15,445,504
  //  15,445,504 : w1c bf16   (32,768)      -> 15,478,272
  //  15,478,272 : w2c bf16   (32,768)      -> 15,511,040
  //  15,511,040 : bn  fp32   (2,048)       -> 15,513,088
  //  15,513,088 : xb  bf16   (12,800,000)  -> 28,313,088
  //  28,313,088 : aggB bf16  (12,800,000)  -> 41,113,088
  //  41,113,088 : t   bf16   (12,800,000)  -> 53,913,088
  //  53,913,088 : r2  bf16   (12,800,000)  -> 66,713,088  (~67 MB)
  int*            tileCnt = (int*)ws;
  int*            tileLo  = (int*)(ws + 613120);
  int*            colBase = (int*)(ws + 1226240);
  int*            deg     = (int*)(ws + 1839360);
  int*            offset  = (int*)(ws + 2239360);
  unsigned*       pairs   = (unsigned*)(ws + 2639360);
  int*            csr     = (int*)(ws + 9045504);
  unsigned short* w1c     = (unsigned short*)(ws + 15445504);
  unsigned short* w2c     = (unsigned short*)(ws + 15478272);
  float*          bn      = (float*)(ws + 15511040);
  unsigned short* xb      = (unsigned short*)(ws + 15513088);
  unsigned short* aggB    = (unsigned short*)(ws + 28313088);
  unsigned short* t       = (unsigned short*)(ws + 41113088);
  unsigned short* r2      = (unsigned short*)(ws + 53913088);

  const int* srcp = ei;
  const int* dstp = ei + NE;

  hipLaunchKernelGGL(k_binprep, dim3(NTIL + NPREP), dim3(256), 0, stream,
                     srcp, dstp, pairs, tileCnt, tileLo,
                     x, xb, w1l, w1r, w2l, w2r, b1l, g1, be1, m1, v1,
                     b2l, g2, be2, m2, v2, w1c, w2c, bn);
  hipLaunchKernelGGL(k_colscan, dim3(NBUK), dim3(256), 0, stream,
                     tileCnt, colBase);
  hipLaunchKernelGGL(k_build, dim3(NBUK), dim3(512), 0, stream,
                     pairs, tileCnt, tileLo, colBase, deg, offset, csr);
  hipLaunchKernelGGL(k_aggregate, dim3(NN / 32), dim3(256), 0, stream,
                     xb, deg, offset, csr, aggB);
  hipLaunchKernelGGL(k_gemm12, dim3((NN / 32 + 7) / 8), dim3(512), 0, stream,
                     aggB, xb, w1c, w2c, bn, t, r2);
  hipLaunchKernelGGL(k_agg2fin, dim3(NN / 32), dim3(256), 0, stream,
                     t, deg, offset, csr, r2, bn, outp);
}